// Round 5
// baseline (2262.046 us; speedup 1.0000x reference)
//
#include <hip/hip_runtime.h>

// ---------------------------------------------------------------------------
// QuantSelfAttention on MI355X (gfx950).  B=4, L=1024, C=1024, H=16, D=64.
// Inputs f32, output f32.  Numerics (validated rounds 4-14, absmax 1.89e-3):
//   - qkv GEMM: fp16x2-split 3-pass MFMA + per-128-K-slab f64 accumulation
//   - q/k as int8 + per-32-group f64 scale; scores = exact int dots, f64 rescale
//   - softmax + round(a*255) in f64
//   - AV = exact integer GEMM via mfma_i32_16x16x32_i8 (r12/r13/r14):
//     out = (s_cc/255) * (sum_m (n_m-128)*iv_m + 128*colsum_cc), all int32.
// Round 15 (round 14 post-mortem: attn_sc was 114us/launch at VGPR=152,
// occupancy 11%, VALUBusy 26% -- the allocator ballooned when the AV tail
// was removed; this was r12's hidden regression too.  The fused r11 attn
// proves the same live state fits in 64 VGPR):
//   - attn_sc: __launch_bounds__(256, 8) forces <=64 VGPR -> 8 waves/SIMD,
//     and LDS 20480 -> exactly 8 blocks/CU.  Code otherwise identical.
//   - attn_av: __launch_bounds__(256, 6) (<=85 VGPR; LDS caps at 6 blk/CU).
//   - gemm reverted to the r11 gemm_qkv3 (presplit measured neutral).
//
// ws byte layout:
//   0         qpre   16MB f32   [aliased as ctx (bf16 8MB) after quant_qk]
//   16777216  kpre   16MB f32   [aliased as IVT (i8 4MB) after quant_k]
//   33554432  vraw   16MB f32   [aliased as Pp (i8 16MB, per-b) after vquant_t]
//   50331648  wprojbf 2MB u16
//   52428800  qint   4MB int8
//   56623104  kT     4MB int32 (64 bh x 16 j x 1024 m)
//   60817408  qs     1MB f64 (131072 groups)
//   61865984  ksT    1MB f64 (64 bh x 2 p x 1024 m)
//   62914560  vs     32KB f64 (4096)
//   62947328  pmax   1MB f32   [aliased as colsum (16KB i32) after vmax_final]
//   high-water 64.0MB (<67.3MB proven)
// ---------------------------------------------------------------------------

typedef unsigned short u16;
typedef unsigned int u32;
typedef __attribute__((ext_vector_type(8))) _Float16 half8;  // 8 f16 (4 VGPRs)
typedef __attribute__((ext_vector_type(4))) float f32x4;     // MFMA accumulator
typedef __attribute__((ext_vector_type(4))) int i32x4;       // i8-MFMA accumulator

__device__ __forceinline__ u16 f2b(float f) {   // f32 -> bf16 RNE
    u32 i;
    __builtin_memcpy(&i, &f, 4);
    return (u16)((i + 0x7FFFu + ((i >> 16) & 1u)) >> 16);
}

__device__ __forceinline__ void split16(float v, u16& hi, u16& lo) {
    _Float16 h = (_Float16)v;
    _Float16 l = (_Float16)(v - (float)h);
    __builtin_memcpy(&hi, &h, 2);
    __builtin_memcpy(&lo, &l, 2);
}

__device__ __forceinline__ int dot4(int a, int b, int c) {
#if __has_builtin(__builtin_amdgcn_sdot4)
    return __builtin_amdgcn_sdot4(a, b, c, false);
#else
    int r = c;
    r += ((a << 24) >> 24) * ((b << 24) >> 24);
    r += ((a << 16) >> 24) * ((b << 16) >> 24);
    r += ((a << 8) >> 24) * ((b << 8) >> 24);
    r += (a >> 24) * (b >> 24);
    return r;
#endif
}

// fast f64 exp for x <= 0 (scores are max-subtracted).  Cody-Waite range
// reduction + degree-10 Taylor (rel err ~2e-13) + exponent bit-add.
// exp(0) == 1.0 exactly.  x < -700 -> 0 (true value < 1e-304; a rounds to 0).
__device__ __forceinline__ double fexp(double x) {
    double kd = rint(x * 1.4426950408889634);
    double r = fma(kd, -6.93147180369123816490e-01, x);
    r = fma(kd, -1.90821492927058770002e-10, r);
    double p = 2.7557319223985888e-07;
    p = fma(p, r, 2.7557319223985890e-06);
    p = fma(p, r, 2.4801587301587302e-05);
    p = fma(p, r, 1.9841269841269841e-04);
    p = fma(p, r, 1.3888888888888889e-03);
    p = fma(p, r, 8.3333333333333333e-03);
    p = fma(p, r, 4.1666666666666664e-02);
    p = fma(p, r, 1.6666666666666666e-01);
    p = fma(p, r, 0.5);
    p = fma(p, r, 1.0);
    p = fma(p, r, 1.0);
    long long bits;
    __builtin_memcpy(&bits, &p, 8);
    bits += ((long long)kd) << 52;
    double e;
    __builtin_memcpy(&e, &bits, 8);
    return (x < -700.0) ? 0.0 : e;
}

// --- K0: w_proj f32 -> bf16 --------------------------------------------------
__global__ __launch_bounds__(256) void cvt_bf16w(u16* __restrict__ dst,
                                                 const float* __restrict__ src, int n) {
    int i = (blockIdx.x * 256 + threadIdx.x) * 4;
    if (i + 3 < n) {
        float4 v = *(const float4*)(src + i);
        ushort4 o;
        o.x = f2b(v.x); o.y = f2b(v.y); o.z = f2b(v.z); o.w = f2b(v.w);
        *(ushort4*)(dst + i) = o;
    }
}

// ---------------------------------------------------------------------------
// K1: qkv = x @ w_qkv^T + bias, fp16x2-split 3-pass MFMA, f64 slab accumulate.
// 128x64 output blocks (grid 48 x 32).  Per-output K-order identical to the
// round-4..14 passing versions -> bit-identical results.
// ---------------------------------------------------------------------------
__global__ __launch_bounds__(256) void gemm_qkv3(const float* __restrict__ A,
                                                 const float* __restrict__ Bm,
                                                 const float* __restrict__ qbias,
                                                 const float* __restrict__ vbias,
                                                 float* __restrict__ qws,
                                                 float* __restrict__ kws,
                                                 float* __restrict__ vws) {
    __shared__ u16 Ah[128 * 32], Al[128 * 32], Bh[64 * 32], Bl[64 * 32];
    const int t = threadIdx.x;
    const int lane = t & 63, w = t >> 6;
    const int srow = t >> 2, scol = (t & 3) * 8;
    const int lm = lane & 15, lk = (lane >> 4) * 8;
    const int bm = blockIdx.y, bn = blockIdx.x;

    const float* ap = A + (size_t)(bm * 128 + srow) * 1024 + scol;
    const float* bp = Bm + (size_t)(bn * 64 + srow) * 1024 + scol;

    double dacc[2][4][4];
#pragma unroll
    for (int i = 0; i < 2; i++)
#pragma unroll
        for (int j = 0; j < 4; j++)
#pragma unroll
            for (int r = 0; r < 4; r++) dacc[i][j][r] = 0.0;

    for (int slab = 0; slab < 8; slab++) {
        f32x4 acc[2][4];
#pragma unroll
        for (int i = 0; i < 2; i++)
#pragma unroll
            for (int j = 0; j < 4; j++) acc[i][j] = (f32x4){0.f, 0.f, 0.f, 0.f};

        for (int kc = 0; kc < 4; kc++) {
            const int k0 = slab * 128 + kc * 32;
            float vreg[3][8];
#pragma unroll
            for (int e = 0; e < 3; e++) {
                const float* src = (e < 2) ? (ap + e * (size_t)64 * 1024 + k0)
                                           : (bp + k0);
                float4 v0 = *(const float4*)(src);
                float4 v1 = *(const float4*)(src + 4);
                vreg[e][0] = v0.x; vreg[e][1] = v0.y; vreg[e][2] = v0.z; vreg[e][3] = v0.w;
                vreg[e][4] = v1.x; vreg[e][5] = v1.y; vreg[e][6] = v1.z; vreg[e][7] = v1.w;
            }
            __syncthreads();
#pragma unroll
            for (int e = 0; e < 3; e++) {
                union { u16 us[8]; uint4 v; } ph, pl;
#pragma unroll
                for (int j = 0; j < 8; j++) split16(vreg[e][j], ph.us[j], pl.us[j]);
                u16* dh = (e < 2) ? Ah : Bh;
                u16* dl = (e < 2) ? Al : Bl;
                int row = (e < 2) ? (srow + e * 64) : srow;
                *(uint4*)(dh + row * 32 + scol) = ph.v;
                *(uint4*)(dl + row * 32 + scol) = pl.v;
            }
            __syncthreads();

            half8 fah[2], fal[2], fbh[4], fbl[4];
#pragma unroll
            for (int i = 0; i < 2; i++) {
                int ra = (w * 32 + i * 16 + lm) * 32 + lk;
                fah[i] = *(const half8*)(Ah + ra);
                fal[i] = *(const half8*)(Al + ra);
            }
#pragma unroll
            for (int i = 0; i < 4; i++) {
                int rb = (i * 16 + lm) * 32 + lk;
                fbh[i] = *(const half8*)(Bh + rb);
                fbl[i] = *(const half8*)(Bl + rb);
            }
#pragma unroll
            for (int mi = 0; mi < 2; mi++)
#pragma unroll
                for (int ni = 0; ni < 4; ni++) {
                    acc[mi][ni] = __builtin_amdgcn_mfma_f32_16x16x32_f16(
                        fal[mi], fbh[ni], acc[mi][ni], 0, 0, 0);
                    acc[mi][ni] = __builtin_amdgcn_mfma_f32_16x16x32_f16(
                        fah[mi], fbl[ni], acc[mi][ni], 0, 0, 0);
                    acc[mi][ni] = __builtin_amdgcn_mfma_f32_16x16x32_f16(
                        fah[mi], fbh[ni], acc[mi][ni], 0, 0, 0);
                }
        }
#pragma unroll
        for (int i = 0; i < 2; i++)
#pragma unroll
            for (int j = 0; j < 4; j++)
#pragma unroll
                for (int r = 0; r < 4; r++) dacc[i][j][r] += (double)acc[i][j][r];
    }

    const int rbase = bm * 128 + w * 32 + (lane >> 4) * 4;
    const int cbase = bn * 64 + lm;
#pragma unroll
    for (int mi = 0; mi < 2; mi++)
#pragma unroll
        for (int ni = 0; ni < 4; ni++) {
            int col = cbase + ni * 16;
            int sel = col >> 10, cc = col & 1023;
            double bias = (sel == 0) ? (double)qbias[cc]
                        : ((sel == 2) ? (double)vbias[cc] : 0.0);
            float* dst = (sel == 0) ? qws : ((sel == 1) ? kws : vws);
#pragma unroll
            for (int r = 0; r < 4; r++) {
                int row = rbase + mi * 16 + r;
                dst[(size_t)row * 1024 + cc] = (float)(dacc[mi][ni][r] + bias);
            }
        }
}

// --- K2a: per-32-group quant of q -> int8 (row-major) + f64 scale ------------
__global__ __launch_bounds__(256) void quant_qk(const float* __restrict__ pre,
                                                signed char* __restrict__ qout,
                                                double* __restrict__ sout) {
    size_t g = (size_t)blockIdx.x * 256 + threadIdx.x;   // 131072 groups
    const float* p = pre + g * 32;
    float v[32];
    float amax = 0.f;
#pragma unroll
    for (int i = 0; i < 8; i++) {
        float4 q4 = ((const float4*)p)[i];
        v[i * 4 + 0] = q4.x; v[i * 4 + 1] = q4.y; v[i * 4 + 2] = q4.z; v[i * 4 + 3] = q4.w;
        amax = fmaxf(amax, fmaxf(fmaxf(fabsf(q4.x), fabsf(q4.y)),
                                 fmaxf(fabsf(q4.z), fabsf(q4.w))));
    }
    double s = fmax((double)amax / 127.0, 1e-8);
    sout[g] = s;
    int pk[8];
#pragma unroll
    for (int i = 0; i < 8; i++) {
        int b0 = (int)fmin(fmax(rint((double)v[i * 4 + 0] / s), -128.0), 127.0);
        int b1 = (int)fmin(fmax(rint((double)v[i * 4 + 1] / s), -128.0), 127.0);
        int b2 = (int)fmin(fmax(rint((double)v[i * 4 + 2] / s), -128.0), 127.0);
        int b3 = (int)fmin(fmax(rint((double)v[i * 4 + 3] / s), -128.0), 127.0);
        pk[i] = (b0 & 255) | ((b1 & 255) << 8) | ((b2 & 255) << 16) | ((b3 & 255) << 24);
    }
    int4* d = (int4*)(qout + g * 32);
    d[0] = make_int4(pk[0], pk[1], pk[2], pk[3]);
    d[1] = make_int4(pk[4], pk[5], pk[6], pk[7]);
}

// --- K2b: per-32-group quant of k -> TRANSPOSED j-major layout ---------------
__global__ __launch_bounds__(256) void quant_k(const float* __restrict__ pre,
                                               int* __restrict__ kT,
                                               double* __restrict__ ksT) {
    size_t g = (size_t)blockIdx.x * 256 + threadIdx.x;   // 131072 groups
    const float* p = pre + g * 32;
    float v[32];
    float amax = 0.f;
#pragma unroll
    for (int i = 0; i < 8; i++) {
        float4 q4 = ((const float4*)p)[i];
        v[i * 4 + 0] = q4.x; v[i * 4 + 1] = q4.y; v[i * 4 + 2] = q4.z; v[i * 4 + 3] = q4.w;
        amax = fmaxf(amax, fmaxf(fmaxf(fabsf(q4.x), fabsf(q4.y)),
                                 fmaxf(fabsf(q4.z), fabsf(q4.w))));
    }
    double s = fmax((double)amax / 127.0, 1e-8);
    int pk[8];
#pragma unroll
    for (int i = 0; i < 8; i++) {
        int b0 = (int)fmin(fmax(rint((double)v[i * 4 + 0] / s), -128.0), 127.0);
        int b1 = (int)fmin(fmax(rint((double)v[i * 4 + 1] / s), -128.0), 127.0);
        int b2 = (int)fmin(fmax(rint((double)v[i * 4 + 2] / s), -128.0), 127.0);
        int b3 = (int)fmin(fmax(rint((double)v[i * 4 + 3] / s), -128.0), 127.0);
        pk[i] = (b0 & 255) | ((b1 & 255) << 8) | ((b2 & 255) << 16) | ((b3 & 255) << 24);
    }
    const int m = (int)((g >> 5) & 1023);
    const int b = (int)(g >> 15);
    const int sub = (int)(g & 31);
    const int h = sub >> 1, pp = sub & 1;
    const int bh = b * 16 + h;
    int* dst = kT + ((size_t)bh * 16 + pp * 8) * 1024 + m;
#pragma unroll
    for (int i = 0; i < 8; i++) dst[i * 1024] = pk[i];
    ksT[((size_t)bh * 2 + pp) * 1024 + m] = s;
}

// --- K3a: partial max|v| over 16-row L-chunks (256 blocks) -------------------
__global__ __launch_bounds__(256) void vmax_part(const float* __restrict__ vws,
                                                 float* __restrict__ pmax) {
    const int lc = blockIdx.x, b = blockIdx.y, t = threadIdx.x;
#pragma unroll
    for (int j = 0; j < 4; j++) {
        int cc = t + j * 256;
        float mx = 0.f;
        for (int l = 0; l < 16; l++)
            mx = fmaxf(mx, fabsf(vws[((size_t)(b * 1024 + lc * 16 + l)) * 1024 + cc]));
        pmax[(size_t)(b * 64 + lc) * 1024 + cc] = mx;
    }
}

// --- K3b: reduce 64 partials -> vs[b*1024+cc] = max(amax/127, eps) f64 -------
__global__ __launch_bounds__(256) void vmax_final(const float* __restrict__ pmax,
                                                  double* __restrict__ vs) {
    int id = blockIdx.x * 256 + threadIdx.x;   // 4096
    int b = id >> 10, cc = id & 1023;
    float mx = 0.f;
    for (int p = 0; p < 64; p++)
        mx = fmaxf(mx, pmax[(size_t)(b * 64 + p) * 1024 + cc]);
    vs[id] = fmax((double)mx / 127.0, 1e-8);
}

// --- K3c: gather-transpose quant v -> IVT[b][cc][m] (f64 decisions) ----------
__global__ __launch_bounds__(256) void vquant_t(const float* __restrict__ vraw,
                                                const double* __restrict__ vs,
                                                signed char* __restrict__ ivt) {
    const int mt = blockIdx.x;            // 0..63  (16-m strip)
    const int ccg = blockIdx.y;           // 0..3   (256-cc group)
    const int b = blockIdx.z;             // 0..3
    const int cc = ccg * 256 + threadIdx.x;
    const double s = vs[b * 1024 + cc];
    const float* src = vraw + ((size_t)(b * 1024) + mt * 16) * 1024 + cc;
    signed char bytes[16];
#pragma unroll
    for (int i = 0; i < 16; i++) {
        float v = src[(size_t)i * 1024];
        bytes[i] = (signed char)(int)fmin(fmax(rint((double)v / s), -128.0), 127.0);
    }
    int4 pk;
    __builtin_memcpy(&pk, bytes, 16);
    *(int4*)(ivt + ((size_t)(b * 1024) + cc) * 1024 + mt * 16) = pk;
}

// --- K3d: colsum[b*1024+cc] = sum_m iv[m][cc] (exact i32) --------------------
__global__ __launch_bounds__(256) void colsum_k(const signed char* __restrict__ ivt,
                                                int* __restrict__ csum) {
    int id = blockIdx.x * 256 + threadIdx.x;   // 4096
    const int4* p = (const int4*)(ivt + (size_t)id * 1024);
    int s = 0;
    for (int i = 0; i < 64; i++) {
        int4 w = p[i];
        s = dot4(w.x, 0x01010101, s);
        s = dot4(w.y, 0x01010101, s);
        s = dot4(w.z, 0x01010101, s);
        s = dot4(w.w, 0x01010101, s);
    }
    csum[id] = s;
}

// ---------------------------------------------------------------------------
// K4a: scores + softmax + n (validated).  One wave per query row, 20KB LDS.
// __launch_bounds__(256, 8): force <=64 VGPR (the fused r11 attn proves the
// live state fits) -> 8 waves/SIMD, 8 blocks/CU.  Writes n-128 to Pp.
// ---------------------------------------------------------------------------
__global__ __launch_bounds__(256, 8) void attn_sc(const signed char* __restrict__ qint,
                                                  const int* __restrict__ kT,
                                                  const double* __restrict__ qs,
                                                  const double* __restrict__ ksT,
                                                  const float* __restrict__ abias,
                                                  signed char* __restrict__ Pp,
                                                  int b) {
    __shared__ int    kTs[16][256];        // 16 KB
    __shared__ double ks0s[256], ks1s[256];//  4 KB
    const int t = threadIdx.x;
    const int wv = t >> 6, lane = t & 63;
    const int qt = blockIdx.x, h = blockIdx.y;
    const int row = qt * 4 + wv;
    const size_t qrow = (size_t)(b * 1024 + row);
    const int bh = b * 16 + h;

    const int* qv = (const int*)(qint + qrow * 1024 + h * 64);
    int qd[16];
#pragma unroll
    for (int j = 0; j < 4; j++) {
        int4 tmp = ((const int4*)qv)[j];
        qd[j * 4 + 0] = tmp.x; qd[j * 4 + 1] = tmp.y;
        qd[j * 4 + 2] = tmp.z; qd[j * 4 + 3] = tmp.w;
    }
    const double sq0 = qs[qrow * 32 + 2 * h], sq1 = qs[qrow * 32 + 2 * h + 1];
    const int* kTg = kT + (size_t)bh * 16384;
    const double* ks0g = ksT + (size_t)(bh * 2) * 1024;
    const double* ks1g = ksT + (size_t)(bh * 2 + 1) * 1024;
    const float* ab = abias + (size_t)row * 1024;

    double sd[16];
    for (int c = 0; c < 4; c++) {
        if (c) __syncthreads();
#pragma unroll
        for (int r = 0; r < 4; r++) {
            const int j = wv * 4 + r;
            int4 val = *(const int4*)(kTg + (size_t)j * 1024 + c * 256 + 4 * lane);
            *(int4*)(&kTs[j][4 * lane]) = val;
        }
        ks0s[t] = ks0g[c * 256 + t];
        ks1s[t] = ks1g[c * 256 + t];
        __syncthreads();
#pragma unroll
        for (int s = 0; s < 4; s++) {
            const int ml = s * 64 + lane;
            int I0 = 0, I1 = 0;
#pragma unroll
            for (int j = 0; j < 8; j++)  I0 = dot4(qd[j], kTs[j][ml], I0);
#pragma unroll
            for (int j = 8; j < 16; j++) I1 = dot4(qd[j], kTs[j][ml], I1);
            sd[c * 4 + s] = 0.125 * (sq0 * ks0s[ml] * (double)I0
                                   + sq1 * ks1s[ml] * (double)I1)
                          + (double)ab[c * 256 + ml];
        }
    }

    // softmax (f64): custom exp, single reciprocal
    double mx = sd[0];
#pragma unroll
    for (int it = 1; it < 16; it++) mx = fmax(mx, sd[it]);
#pragma unroll
    for (int off = 1; off < 64; off <<= 1) mx = fmax(mx, __shfl_xor(mx, off));
    double sum = 0.0;
#pragma unroll
    for (int it = 0; it < 16; it++) {
        double e = fexp(sd[it] - mx);
        sd[it] = e;
        sum += e;
    }
#pragma unroll
    for (int off = 1; off < 64; off <<= 1) sum += __shfl_xor(sum, off);
    const double inv = 1.0 / sum;

    // n = clamp(round(a*255),0,255); store n-128 as i8 (coalesced 64B/wave)
    signed char* prow = Pp + ((size_t)h * 1024 + row) * 1024;
#pragma unroll
    for (int it = 0; it < 16; it++) {
        double a = sd[it] * inv;
        double nd = fmin(fmax(rint(a * 255.0), 0.0), 255.0);
        int ni = (int)nd;
        prow[it * 64 + lane] = (signed char)(ni - 128);
    }
}

// ---------------------------------------------------------------------------
// K4b: AV as exact-int i8 MFMA (validated r13/r14).  Block = (qt,h): stage P
// tile 16x1024 from Pp (coalesced, (row<<3) XOR swizzle); V chunks from IVT
// with (vrow&15)<<3 swizzle; 32 MFMAs; epilogue (S+128*colsum)*s/255.
// LDS 24KB -> 6 blocks/CU; launch_bounds(256,6) keeps VGPR <= 85.
// ---------------------------------------------------------------------------
__global__ __launch_bounds__(256, 6) void attn_av(const signed char* __restrict__ Pp,
                                                  const signed char* __restrict__ ivt,
                                                  const double* __restrict__ vs,
                                                  const int* __restrict__ csum,
                                                  u16* __restrict__ ctx,
                                                  int b) {
    __shared__ __align__(16) char smem[24576];
    signed char* Pl = (signed char*)smem;               // [16][1024] swizzled
    char*        Bv = smem + 16384;                     // [64][128]  swizzled
    const int t = threadIdx.x;
    const int wv = t >> 6, lane = t & 63;
    const int qt = blockIdx.x, h = blockIdx.y;

    // stage P tile (16 rows x 1024B), coalesced 64B/thread, 8B-XOR swizzle
    {
        const int row = t >> 4, seg = (t & 15) * 64;
        const signed char* src = Pp + ((size_t)h * 1024 + qt * 16 + row) * 1024 + seg;
        const int x = row << 3;
        ulonglong2 q0 = *(const ulonglong2*)(src);
        ulonglong2 q1 = *(const ulonglong2*)(src + 16);
        ulonglong2 q2 = *(const ulonglong2*)(src + 32);
        ulonglong2 q3 = *(const ulonglong2*)(src + 48);
        signed char* dr = Pl + row * 1024;
        *(unsigned long long*)(dr + ((seg +  0) ^ x)) = q0.x;
        *(unsigned long long*)(dr + ((seg +  8) ^ x)) = q0.y;
        *(unsigned long long*)(dr + ((seg + 16) ^ x)) = q1.x;
        *(unsigned long long*)(dr + ((seg + 24) ^ x)) = q1.y;
        *(unsigned long long*)(dr + ((seg + 32) ^ x)) = q2.x;
        *(unsigned long long*)(dr + ((seg + 40) ^ x)) = q2.y;
        *(unsigned long long*)(dr + ((seg + 48) ^ x)) = q3.x;
        *(unsigned long long*)(dr + ((seg + 56) ^ x)) = q3.y;
    }

    const int col = lane & 15;
    const int cc = h * 64 + wv * 16 + col;
    const signed char* bg = ivt + ((size_t)(b * 1024) + h * 64) * 1024;
    const int arow = lane & 15;
    const int xa = arow << 3;
    const int browo = (wv * 16 + col) * 128;
    const int xb = col << 3;
    const int kq = (lane >> 4) * 8;

    i32x4 acc = (i32x4){0, 0, 0, 0};
    for (int kc = 0; kc < 8; kc++) {
        __syncthreads();   // Pl ready (kc=0) / prev MFMA reads done
        {   // stage Bv[64][128] from IVT, coalesced, swizzled
            const int vrow = t >> 2, seg = (t & 3) * 32;
            const signed char* src = bg + (size_t)vrow * 1024 + kc * 128 + seg;
            ulonglong2 q0 = *(const ulonglong2*)(src);
            ulonglong2 q1 = *(const ulonglong2*)(src + 16);
            const int xv = (vrow & 15) << 3;
            char* drow = Bv + vrow * 128;
            *(unsigned long long*)(drow + ((seg +  0) ^ xv)) = q0.x;
            *(unsigned long long*)(drow + ((seg +  8) ^ xv)) = q0.y;
            *(unsigned long long*)(drow + ((seg + 16) ^ xv)) = q1.x;
            *(unsigned long long*)(drow + ((seg + 24) ^ xv)) = q1.y;
        }
        __syncthreads();
#pragma unroll
        for (int ks = 0; ks < 4; ks++) {
            const int ko = ks * 32 + kq;
            long a, bvv;
            __builtin_memcpy(&a,   Pl + arow * 1024 + ((kc * 128 + ko) ^ xa), 8);
            __builtin_memcpy(&bvv, Bv + browo + (ko ^ xb), 8);
            acc = __builtin_amdgcn_mfma_i32_16x16x32_i8(a, bvv, acc, 0, 0, 0);
        }
    }

    // epilogue (validated round 12): out = (S + 128*colsum) * s / 255
    const double sc = vs[b * 1024 + cc] * (1.0 / 255.0);
    const int cs = 128 * csum[b * 1024 + cc];
    const int rbase = qt * 16 + (lane >> 4) * 4;
#pragma unroll
    for (int r = 0; r < 4; r++) {
        int S = acc[r] + cs;
        double val = (double)S * sc;
        ctx[((size_t)(b * 1024) + rbase + r) * 1024 + cc] = f2b((float)val);
    }
}

// --- K5: out = ctx @ w_proj^T + b_proj, bf16 MFMA (post-cliff) ---------------
__global__ __launch_bounds__(256) void gemm_proj(const u16* __restrict__ ctx,
                                                 const u16* __restrict__ wproj,
                                                 const float* __restrict__ bproj,
                                                 float* __restrict__ out) {
    typedef __attribute__((ext_vector_type(8))) short short8;
    __shared__ u16 As[128 * 32], Bs[128 * 32];
    f32x4 acc[4][4];
#pragma unroll
    for (int i = 0; i < 4; i++)
#pragma unroll
        for (int j = 0; j < 4; j++) acc[i][j] = (f32x4){0.f, 0.f, 0.f, 0.f};

    const int t = threadIdx.x;
    const int lane = t & 63, w = t >> 6;
    const int wm = w >> 1, wn = w & 1;
    const int srow = t >> 2, scol = (t & 3) * 8;
    const int lm = lane & 15, lk = (lane >> 4) * 8;
    const int bm = blockIdx.y, bn = blockIdx.x;
    const u16* ap = ctx + (size_t)(bm * 128 + srow) * 1024 + scol;
    const u16* bp = wproj + (size_t)(bn * 128 + srow) * 1024 + scol;

    for (int k0 = 0; k0 < 1024; k0 += 32) {
        uint4 a0 = *(const uint4*)(ap + k0);
        uint4 a1 = *(const uint4*)(ap + (size_t)64 * 1024 + k0);
        uint4 b0 = *(const uint4*)(bp + k0);
        uint4 b1 = *(const uint4*)(bp + (size_t)64 * 1024 + k0);
        __syncthreads();
        *(uint4*)(As + srow * 32 + scol) = a0;
        *(uint4*)(As + (srow + 64) * 32 + scol) = a1;
        *(uint4*)(Bs + srow * 32 + scol) = b0;
        *(uint4*)(Bs + (srow + 64) * 32 + scol) = b1;
        __syncthreads();
        short8 af[4], bfr[4];
#pragma unroll
        for (int i = 0; i < 4; i++) {
            af[i]  = *(const short8*)(As + (wm * 64 + i * 16 + lm) * 32 + lk);
            bfr[i] = *(const short8*)(Bs + (wn * 64 + i * 16 + lm) * 32 + lk);
        }
#pragma unroll
        for (int mi = 0; mi < 4; mi++)
#pragma unroll
            for (int ni = 0; ni < 4; ni++)
                acc[mi][ni] = __builtin_amdgcn_mfma_f32_16x16x32_bf16(
                    af[mi], bfr[ni], acc[mi][ni], 0, 0, 0);
    }

    const int rbase = bm * 128 + wm * 64 + (lane >> 4) * 4;
    const int cbase = bn * 128 + wn * 64 + lm;
#pragma unroll
    for (int mi = 0; mi < 4; mi++)
#pragma unroll
        for (int ni = 0; ni < 4; ni++) {
            int col = cbase + ni * 16;
            float bias = bproj[col];
#pragma unroll
            for (int r = 0; r < 4; r++) {
                int row = rbase + mi * 16 + r;
                out[(size_t)row * 1024 + col] = acc[mi][ni][r] + bias;
            }
        }
}

// ---------------------------------------------------------------------------
extern "C" void kernel_launch(void* const* d_in, const int* in_sizes, int n_in,
                              void* d_out, int out_size, void* d_ws, size_t ws_size,
                              hipStream_t stream) {
    const float* x     = (const float*)d_in[0];
    const float* abias = (const float*)d_in[1];
    const float* wqkv  = (const float*)d_in[2];
    const float* qbias = (const float*)d_in[3];
    const float* vbias = (const float*)d_in[4];
    const float* wproj = (const float*)d_in[5];
    const float* bproj = (const float*)d_in[6];
    float* out = (float*)d_out;

    char* ws = (char*)d_ws;
    float*       qpre    = (float*)(ws + 0);
    float*       kpre    = (float*)(ws + 16777216);
    float*       vraw    = (float*)(ws + 33554432);
    u16*         wprojbf = (u16*)  (ws + 50331648);
    signed char* qint    = (signed char*)(ws + 52428800);
    int*         kT      = (int*)  (ws + 56623104);
    double*      qs      = (double*)(ws + 60817408);
    double*      ksT     = (double*)(ws + 61865984);
    double*      vs      = (double*)(ws + 62914560);
    float*       pmax    = (float*)(ws + 62947328);        // 1MB
    // aliases (live ranges disjoint, stream-ordered):
    u16*         ctx     = (u16*)(ws + 0);                 // over qpre
    signed char* ivt     = (signed char*)(ws + 16777216);  // over kpre (4MB)
    signed char* Pp      = (signed char*)(ws + 33554432);  // over vraw (per-b)
    int*         csum    = (int*)(ws + 62947328);          // over pmax (16KB)

    cvt_bf16w<<<1024, 256, 0, stream>>>(wprojbf, wproj, 1048576);
    gemm_qkv3<<<dim3(48, 32), 256, 0, stream>>>(x, wqkv, qbias, vbias,
                                                qpre, kpre, vraw);
    quant_qk<<<512, 256, 0, stream>>>(qpre, qint, qs);
    quant_k<<<512, 256, 0, stream>>>(kpre, kT, ksT);
    vmax_part<<<dim3(64, 4), 256, 0, stream>>>(vraw, pmax);
    vmax_final<<<16, 256, 0, stream>>>(pmax, vs);
    vquant_t<<<dim3(64, 4, 4), 256, 0, stream>>>(vraw, vs, ivt);
    colsum_k<<<16, 256, 0, stream>>>(ivt, csum);
    for (int b = 0; b < 4; b++) {
        attn_sc<<<dim3(256, 16), 256, 0, stream>>>(qint, kT, qs, ksT, abias, Pp, b);
        attn_av<<<dim3(64, 16), 256, 0, stream>>>(Pp, ivt, vs, csum, ctx, b);
    }
    gemm_proj<<<dim3(8, 32), 256, 0, stream>>>(ctx, wprojbf, bproj, out);
}

// Round 6
// 2109.552 us; speedup vs baseline: 1.0723x; 1.0723x over previous
//
#include <hip/hip_runtime.h>

// ---------------------------------------------------------------------------
// QuantSelfAttention on MI355X (gfx950).  B=4, L=1024, C=1024, H=16, D=64.
// Inputs f32, output f32.  Numerics (validated rounds 4-15, absmax 1.89e-3):
//   - qkv GEMM: fp16x2-split 3-pass MFMA + per-128-K-slab f64 accumulation
//   - q/k as int8 + per-32-group f64 scale; scores = exact int dots, f64 rescale
//   - softmax + round(a*255) in f64
//   - AV = exact integer GEMM via mfma_i32_16x16x32_i8:
//     out = (s_cc/255) * (sum_m (n_m-128)*iv_m + 128*colsum_cc), all int32.
// Round 16 (round 15 post-mortem: launch_bounds(256,8) forced VGPR=32 ->
// sd[16] f64 spilled to scratch; FETCH_SIZE 7.9MB -> 556MB/dispatch, HBM
// 3.4TB/s, attn_sc 485us.  Live state needs ~75-85 VGPR):
//   - attn_sc: __launch_bounds__(256, 6) -> VGPR cap 85 (state fits, no
//     spill), 6 blocks/CU = 24 waves/CU.  Code otherwise identical.
//   - everything else unchanged from round 15.
//
// ws byte layout:
//   0         qpre   16MB f32   [aliased as ctx (bf16 8MB) after quant_qk]
//   16777216  kpre   16MB f32   [aliased as IVT (i8 4MB) after quant_k]
//   33554432  vraw   16MB f32   [aliased as Pp (i8 16MB, per-b) after vquant_t]
//   50331648  wprojbf 2MB u16
//   52428800  qint   4MB int8
//   56623104  kT     4MB int32 (64 bh x 16 j x 1024 m)
//   60817408  qs     1MB f64 (131072 groups)
//   61865984  ksT    1MB f64 (64 bh x 2 p x 1024 m)
//   62914560  vs     32KB f64 (4096)
//   62947328  pmax   1MB f32   [aliased as colsum (16KB i32) after vmax_final]
//   high-water 64.0MB (<67.3MB proven)
// ---------------------------------------------------------------------------

typedef unsigned short u16;
typedef unsigned int u32;
typedef __attribute__((ext_vector_type(8))) _Float16 half8;  // 8 f16 (4 VGPRs)
typedef __attribute__((ext_vector_type(4))) float f32x4;     // MFMA accumulator
typedef __attribute__((ext_vector_type(4))) int i32x4;       // i8-MFMA accumulator

__device__ __forceinline__ u16 f2b(float f) {   // f32 -> bf16 RNE
    u32 i;
    __builtin_memcpy(&i, &f, 4);
    return (u16)((i + 0x7FFFu + ((i >> 16) & 1u)) >> 16);
}

__device__ __forceinline__ void split16(float v, u16& hi, u16& lo) {
    _Float16 h = (_Float16)v;
    _Float16 l = (_Float16)(v - (float)h);
    __builtin_memcpy(&hi, &h, 2);
    __builtin_memcpy(&lo, &l, 2);
}

__device__ __forceinline__ int dot4(int a, int b, int c) {
#if __has_builtin(__builtin_amdgcn_sdot4)
    return __builtin_amdgcn_sdot4(a, b, c, false);
#else
    int r = c;
    r += ((a << 24) >> 24) * ((b << 24) >> 24);
    r += ((a << 16) >> 24) * ((b << 16) >> 24);
    r += ((a << 8) >> 24) * ((b << 8) >> 24);
    r += (a >> 24) * (b >> 24);
    return r;
#endif
}

// fast f64 exp for x <= 0 (scores are max-subtracted).  Cody-Waite range
// reduction + degree-10 Taylor (rel err ~2e-13) + exponent bit-add.
// exp(0) == 1.0 exactly.  x < -700 -> 0 (true value < 1e-304; a rounds to 0).
__device__ __forceinline__ double fexp(double x) {
    double kd = rint(x * 1.4426950408889634);
    double r = fma(kd, -6.93147180369123816490e-01, x);
    r = fma(kd, -1.90821492927058770002e-10, r);
    double p = 2.7557319223985888e-07;
    p = fma(p, r, 2.7557319223985890e-06);
    p = fma(p, r, 2.4801587301587302e-05);
    p = fma(p, r, 1.9841269841269841e-04);
    p = fma(p, r, 1.3888888888888889e-03);
    p = fma(p, r, 8.3333333333333333e-03);
    p = fma(p, r, 4.1666666666666664e-02);
    p = fma(p, r, 1.6666666666666666e-01);
    p = fma(p, r, 0.5);
    p = fma(p, r, 1.0);
    p = fma(p, r, 1.0);
    long long bits;
    __builtin_memcpy(&bits, &p, 8);
    bits += ((long long)kd) << 52;
    double e;
    __builtin_memcpy(&e, &bits, 8);
    return (x < -700.0) ? 0.0 : e;
}

// --- K0: w_proj f32 -> bf16 --------------------------------------------------
__global__ __launch_bounds__(256) void cvt_bf16w(u16* __restrict__ dst,
                                                 const float* __restrict__ src, int n) {
    int i = (blockIdx.x * 256 + threadIdx.x) * 4;
    if (i + 3 < n) {
        float4 v = *(const float4*)(src + i);
        ushort4 o;
        o.x = f2b(v.x); o.y = f2b(v.y); o.z = f2b(v.z); o.w = f2b(v.w);
        *(ushort4*)(dst + i) = o;
    }
}

// ---------------------------------------------------------------------------
// K1: qkv = x @ w_qkv^T + bias, fp16x2-split 3-pass MFMA, f64 slab accumulate.
// 128x64 output blocks (grid 48 x 32).  Per-output K-order identical to the
// round-4..15 passing versions -> bit-identical results.
// ---------------------------------------------------------------------------
__global__ __launch_bounds__(256) void gemm_qkv3(const float* __restrict__ A,
                                                 const float* __restrict__ Bm,
                                                 const float* __restrict__ qbias,
                                                 const float* __restrict__ vbias,
                                                 float* __restrict__ qws,
                                                 float* __restrict__ kws,
                                                 float* __restrict__ vws) {
    __shared__ u16 Ah[128 * 32], Al[128 * 32], Bh[64 * 32], Bl[64 * 32];
    const int t = threadIdx.x;
    const int lane = t & 63, w = t >> 6;
    const int srow = t >> 2, scol = (t & 3) * 8;
    const int lm = lane & 15, lk = (lane >> 4) * 8;
    const int bm = blockIdx.y, bn = blockIdx.x;

    const float* ap = A + (size_t)(bm * 128 + srow) * 1024 + scol;
    const float* bp = Bm + (size_t)(bn * 64 + srow) * 1024 + scol;

    double dacc[2][4][4];
#pragma unroll
    for (int i = 0; i < 2; i++)
#pragma unroll
        for (int j = 0; j < 4; j++)
#pragma unroll
            for (int r = 0; r < 4; r++) dacc[i][j][r] = 0.0;

    for (int slab = 0; slab < 8; slab++) {
        f32x4 acc[2][4];
#pragma unroll
        for (int i = 0; i < 2; i++)
#pragma unroll
            for (int j = 0; j < 4; j++) acc[i][j] = (f32x4){0.f, 0.f, 0.f, 0.f};

        for (int kc = 0; kc < 4; kc++) {
            const int k0 = slab * 128 + kc * 32;
            float vreg[3][8];
#pragma unroll
            for (int e = 0; e < 3; e++) {
                const float* src = (e < 2) ? (ap + e * (size_t)64 * 1024 + k0)
                                           : (bp + k0);
                float4 v0 = *(const float4*)(src);
                float4 v1 = *(const float4*)(src + 4);
                vreg[e][0] = v0.x; vreg[e][1] = v0.y; vreg[e][2] = v0.z; vreg[e][3] = v0.w;
                vreg[e][4] = v1.x; vreg[e][5] = v1.y; vreg[e][6] = v1.z; vreg[e][7] = v1.w;
            }
            __syncthreads();
#pragma unroll
            for (int e = 0; e < 3; e++) {
                union { u16 us[8]; uint4 v; } ph, pl;
#pragma unroll
                for (int j = 0; j < 8; j++) split16(vreg[e][j], ph.us[j], pl.us[j]);
                u16* dh = (e < 2) ? Ah : Bh;
                u16* dl = (e < 2) ? Al : Bl;
                int row = (e < 2) ? (srow + e * 64) : srow;
                *(uint4*)(dh + row * 32 + scol) = ph.v;
                *(uint4*)(dl + row * 32 + scol) = pl.v;
            }
            __syncthreads();

            half8 fah[2], fal[2], fbh[4], fbl[4];
#pragma unroll
            for (int i = 0; i < 2; i++) {
                int ra = (w * 32 + i * 16 + lm) * 32 + lk;
                fah[i] = *(const half8*)(Ah + ra);
                fal[i] = *(const half8*)(Al + ra);
            }
#pragma unroll
            for (int i = 0; i < 4; i++) {
                int rb = (i * 16 + lm) * 32 + lk;
                fbh[i] = *(const half8*)(Bh + rb);
                fbl[i] = *(const half8*)(Bl + rb);
            }
#pragma unroll
            for (int mi = 0; mi < 2; mi++)
#pragma unroll
                for (int ni = 0; ni < 4; ni++) {
                    acc[mi][ni] = __builtin_amdgcn_mfma_f32_16x16x32_f16(
                        fal[mi], fbh[ni], acc[mi][ni], 0, 0, 0);
                    acc[mi][ni] = __builtin_amdgcn_mfma_f32_16x16x32_f16(
                        fah[mi], fbl[ni], acc[mi][ni], 0, 0, 0);
                    acc[mi][ni] = __builtin_amdgcn_mfma_f32_16x16x32_f16(
                        fah[mi], fbh[ni], acc[mi][ni], 0, 0, 0);
                }
        }
#pragma unroll
        for (int i = 0; i < 2; i++)
#pragma unroll
            for (int j = 0; j < 4; j++)
#pragma unroll
                for (int r = 0; r < 4; r++) dacc[i][j][r] += (double)acc[i][j][r];
    }

    const int rbase = bm * 128 + w * 32 + (lane >> 4) * 4;
    const int cbase = bn * 64 + lm;
#pragma unroll
    for (int mi = 0; mi < 2; mi++)
#pragma unroll
        for (int ni = 0; ni < 4; ni++) {
            int col = cbase + ni * 16;
            int sel = col >> 10, cc = col & 1023;
            double bias = (sel == 0) ? (double)qbias[cc]
                        : ((sel == 2) ? (double)vbias[cc] : 0.0);
            float* dst = (sel == 0) ? qws : ((sel == 1) ? kws : vws);
#pragma unroll
            for (int r = 0; r < 4; r++) {
                int row = rbase + mi * 16 + r;
                dst[(size_t)row * 1024 + cc] = (float)(dacc[mi][ni][r] + bias);
            }
        }
}

// --- K2a: per-32-group quant of q -> int8 (row-major) + f64 scale ------------
__global__ __launch_bounds__(256) void quant_qk(const float* __restrict__ pre,
                                                signed char* __restrict__ qout,
                                                double* __restrict__ sout) {
    size_t g = (size_t)blockIdx.x * 256 + threadIdx.x;   // 131072 groups
    const float* p = pre + g * 32;
    float v[32];
    float amax = 0.f;
#pragma unroll
    for (int i = 0; i < 8; i++) {
        float4 q4 = ((const float4*)p)[i];
        v[i * 4 + 0] = q4.x; v[i * 4 + 1] = q4.y; v[i * 4 + 2] = q4.z; v[i * 4 + 3] = q4.w;
        amax = fmaxf(amax, fmaxf(fmaxf(fabsf(q4.x), fabsf(q4.y)),
                                 fmaxf(fabsf(q4.z), fabsf(q4.w))));
    }
    double s = fmax((double)amax / 127.0, 1e-8);
    sout[g] = s;
    int pk[8];
#pragma unroll
    for (int i = 0; i < 8; i++) {
        int b0 = (int)fmin(fmax(rint((double)v[i * 4 + 0] / s), -128.0), 127.0);
        int b1 = (int)fmin(fmax(rint((double)v[i * 4 + 1] / s), -128.0), 127.0);
        int b2 = (int)fmin(fmax(rint((double)v[i * 4 + 2] / s), -128.0), 127.0);
        int b3 = (int)fmin(fmax(rint((double)v[i * 4 + 3] / s), -128.0), 127.0);
        pk[i] = (b0 & 255) | ((b1 & 255) << 8) | ((b2 & 255) << 16) | ((b3 & 255) << 24);
    }
    int4* d = (int4*)(qout + g * 32);
    d[0] = make_int4(pk[0], pk[1], pk[2], pk[3]);
    d[1] = make_int4(pk[4], pk[5], pk[6], pk[7]);
}

// --- K2b: per-32-group quant of k -> TRANSPOSED j-major layout ---------------
__global__ __launch_bounds__(256) void quant_k(const float* __restrict__ pre,
                                               int* __restrict__ kT,
                                               double* __restrict__ ksT) {
    size_t g = (size_t)blockIdx.x * 256 + threadIdx.x;   // 131072 groups
    const float* p = pre + g * 32;
    float v[32];
    float amax = 0.f;
#pragma unroll
    for (int i = 0; i < 8; i++) {
        float4 q4 = ((const float4*)p)[i];
        v[i * 4 + 0] = q4.x; v[i * 4 + 1] = q4.y; v[i * 4 + 2] = q4.z; v[i * 4 + 3] = q4.w;
        amax = fmaxf(amax, fmaxf(fmaxf(fabsf(q4.x), fabsf(q4.y)),
                                 fmaxf(fabsf(q4.z), fabsf(q4.w))));
    }
    double s = fmax((double)amax / 127.0, 1e-8);
    int pk[8];
#pragma unroll
    for (int i = 0; i < 8; i++) {
        int b0 = (int)fmin(fmax(rint((double)v[i * 4 + 0] / s), -128.0), 127.0);
        int b1 = (int)fmin(fmax(rint((double)v[i * 4 + 1] / s), -128.0), 127.0);
        int b2 = (int)fmin(fmax(rint((double)v[i * 4 + 2] / s), -128.0), 127.0);
        int b3 = (int)fmin(fmax(rint((double)v[i * 4 + 3] / s), -128.0), 127.0);
        pk[i] = (b0 & 255) | ((b1 & 255) << 8) | ((b2 & 255) << 16) | ((b3 & 255) << 24);
    }
    const int m = (int)((g >> 5) & 1023);
    const int b = (int)(g >> 15);
    const int sub = (int)(g & 31);
    const int h = sub >> 1, pp = sub & 1;
    const int bh = b * 16 + h;
    int* dst = kT + ((size_t)bh * 16 + pp * 8) * 1024 + m;
#pragma unroll
    for (int i = 0; i < 8; i++) dst[i * 1024] = pk[i];
    ksT[((size_t)bh * 2 + pp) * 1024 + m] = s;
}

// --- K3a: partial max|v| over 16-row L-chunks (256 blocks) -------------------
__global__ __launch_bounds__(256) void vmax_part(const float* __restrict__ vws,
                                                 float* __restrict__ pmax) {
    const int lc = blockIdx.x, b = blockIdx.y, t = threadIdx.x;
#pragma unroll
    for (int j = 0; j < 4; j++) {
        int cc = t + j * 256;
        float mx = 0.f;
        for (int l = 0; l < 16; l++)
            mx = fmaxf(mx, fabsf(vws[((size_t)(b * 1024 + lc * 16 + l)) * 1024 + cc]));
        pmax[(size_t)(b * 64 + lc) * 1024 + cc] = mx;
    }
}

// --- K3b: reduce 64 partials -> vs[b*1024+cc] = max(amax/127, eps) f64 -------
__global__ __launch_bounds__(256) void vmax_final(const float* __restrict__ pmax,
                                                  double* __restrict__ vs) {
    int id = blockIdx.x * 256 + threadIdx.x;   // 4096
    int b = id >> 10, cc = id & 1023;
    float mx = 0.f;
    for (int p = 0; p < 64; p++)
        mx = fmaxf(mx, pmax[(size_t)(b * 64 + p) * 1024 + cc]);
    vs[id] = fmax((double)mx / 127.0, 1e-8);
}

// --- K3c: gather-transpose quant v -> IVT[b][cc][m] (f64 decisions) ----------
__global__ __launch_bounds__(256) void vquant_t(const float* __restrict__ vraw,
                                                const double* __restrict__ vs,
                                                signed char* __restrict__ ivt) {
    const int mt = blockIdx.x;            // 0..63  (16-m strip)
    const int ccg = blockIdx.y;           // 0..3   (256-cc group)
    const int b = blockIdx.z;             // 0..3
    const int cc = ccg * 256 + threadIdx.x;
    const double s = vs[b * 1024 + cc];
    const float* src = vraw + ((size_t)(b * 1024) + mt * 16) * 1024 + cc;
    signed char bytes[16];
#pragma unroll
    for (int i = 0; i < 16; i++) {
        float v = src[(size_t)i * 1024];
        bytes[i] = (signed char)(int)fmin(fmax(rint((double)v / s), -128.0), 127.0);
    }
    int4 pk;
    __builtin_memcpy(&pk, bytes, 16);
    *(int4*)(ivt + ((size_t)(b * 1024) + cc) * 1024 + mt * 16) = pk;
}

// --- K3d: colsum[b*1024+cc] = sum_m iv[m][cc] (exact i32) --------------------
__global__ __launch_bounds__(256) void colsum_k(const signed char* __restrict__ ivt,
                                                int* __restrict__ csum) {
    int id = blockIdx.x * 256 + threadIdx.x;   // 4096
    const int4* p = (const int4*)(ivt + (size_t)id * 1024);
    int s = 0;
    for (int i = 0; i < 64; i++) {
        int4 w = p[i];
        s = dot4(w.x, 0x01010101, s);
        s = dot4(w.y, 0x01010101, s);
        s = dot4(w.z, 0x01010101, s);
        s = dot4(w.w, 0x01010101, s);
    }
    csum[id] = s;
}

// ---------------------------------------------------------------------------
// K4a: scores + softmax + n (validated).  One wave per query row, 20KB LDS.
// __launch_bounds__(256, 6): VGPR cap 85 -- the sd[16] f64 + qd[16] live
// state needs ~80, fits without spill (r15's cap of 8 -> 32 VGPR spilled
// everything to scratch: 556MB FETCH/dispatch).  6 blocks/CU = 24 waves.
// ---------------------------------------------------------------------------
__global__ __launch_bounds__(256, 6) void attn_sc(const signed char* __restrict__ qint,
                                                  const int* __restrict__ kT,
                                                  const double* __restrict__ qs,
                                                  const double* __restrict__ ksT,
                                                  const float* __restrict__ abias,
                                                  signed char* __restrict__ Pp,
                                                  int b) {
    __shared__ int    kTs[16][256];        // 16 KB
    __shared__ double ks0s[256], ks1s[256];//  4 KB
    const int t = threadIdx.x;
    const int wv = t >> 6, lane = t & 63;
    const int qt = blockIdx.x, h = blockIdx.y;
    const int row = qt * 4 + wv;
    const size_t qrow = (size_t)(b * 1024 + row);
    const int bh = b * 16 + h;

    const int* qv = (const int*)(qint + qrow * 1024 + h * 64);
    int qd[16];
#pragma unroll
    for (int j = 0; j < 4; j++) {
        int4 tmp = ((const int4*)qv)[j];
        qd[j * 4 + 0] = tmp.x; qd[j * 4 + 1] = tmp.y;
        qd[j * 4 + 2] = tmp.z; qd[j * 4 + 3] = tmp.w;
    }
    const double sq0 = qs[qrow * 32 + 2 * h], sq1 = qs[qrow * 32 + 2 * h + 1];
    const int* kTg = kT + (size_t)bh * 16384;
    const double* ks0g = ksT + (size_t)(bh * 2) * 1024;
    const double* ks1g = ksT + (size_t)(bh * 2 + 1) * 1024;
    const float* ab = abias + (size_t)row * 1024;

    double sd[16];
    for (int c = 0; c < 4; c++) {
        if (c) __syncthreads();
#pragma unroll
        for (int r = 0; r < 4; r++) {
            const int j = wv * 4 + r;
            int4 val = *(const int4*)(kTg + (size_t)j * 1024 + c * 256 + 4 * lane);
            *(int4*)(&kTs[j][4 * lane]) = val;
        }
        ks0s[t] = ks0g[c * 256 + t];
        ks1s[t] = ks1g[c * 256 + t];
        __syncthreads();
#pragma unroll
        for (int s = 0; s < 4; s++) {
            const int ml = s * 64 + lane;
            int I0 = 0, I1 = 0;
#pragma unroll
            for (int j = 0; j < 8; j++)  I0 = dot4(qd[j], kTs[j][ml], I0);
#pragma unroll
            for (int j = 8; j < 16; j++) I1 = dot4(qd[j], kTs[j][ml], I1);
            sd[c * 4 + s] = 0.125 * (sq0 * ks0s[ml] * (double)I0
                                   + sq1 * ks1s[ml] * (double)I1)
                          + (double)ab[c * 256 + ml];
        }
    }

    // softmax (f64): custom exp, single reciprocal
    double mx = sd[0];
#pragma unroll
    for (int it = 1; it < 16; it++) mx = fmax(mx, sd[it]);
#pragma unroll
    for (int off = 1; off < 64; off <<= 1) mx = fmax(mx, __shfl_xor(mx, off));
    double sum = 0.0;
#pragma unroll
    for (int it = 0; it < 16; it++) {
        double e = fexp(sd[it] - mx);
        sd[it] = e;
        sum += e;
    }
#pragma unroll
    for (int off = 1; off < 64; off <<= 1) sum += __shfl_xor(sum, off);
    const double inv = 1.0 / sum;

    // n = clamp(round(a*255),0,255); store n-128 as i8 (coalesced 64B/wave)
    signed char* prow = Pp + ((size_t)h * 1024 + row) * 1024;
#pragma unroll
    for (int it = 0; it < 16; it++) {
        double a = sd[it] * inv;
        double nd = fmin(fmax(rint(a * 255.0), 0.0), 255.0);
        int ni = (int)nd;
        prow[it * 64 + lane] = (signed char)(ni - 128);
    }
}

// ---------------------------------------------------------------------------
// K4b: AV as exact-int i8 MFMA (validated r13/r14).  Block = (qt,h): stage P
// tile 16x1024 from Pp (coalesced, (row<<3) XOR swizzle); V chunks from IVT
// with (vrow&15)<<3 swizzle; 32 MFMAs; epilogue (S+128*colsum)*s/255.
// LDS 24KB -> 6 blocks/CU; launch_bounds(256,6) keeps VGPR <= 85.
// ---------------------------------------------------------------------------
__global__ __launch_bounds__(256, 6) void attn_av(const signed char* __restrict__ Pp,
                                                  const signed char* __restrict__ ivt,
                                                  const double* __restrict__ vs,
                                                  const int* __restrict__ csum,
                                                  u16* __restrict__ ctx,
                                                  int b) {
    __shared__ __align__(16) char smem[24576];
    signed char* Pl = (signed char*)smem;               // [16][1024] swizzled
    char*        Bv = smem + 16384;                     // [64][128]  swizzled
    const int t = threadIdx.x;
    const int wv = t >> 6, lane = t & 63;
    const int qt = blockIdx.x, h = blockIdx.y;

    // stage P tile (16 rows x 1024B), coalesced 64B/thread, 8B-XOR swizzle
    {
        const int row = t >> 4, seg = (t & 15) * 64;
        const signed char* src = Pp + ((size_t)h * 1024 + qt * 16 + row) * 1024 + seg;
        const int x = row << 3;
        ulonglong2 q0 = *(const ulonglong2*)(src);
        ulonglong2 q1 = *(const ulonglong2*)(src + 16);
        ulonglong2 q2 = *(const ulonglong2*)(src + 32);
        ulonglong2 q3 = *(const ulonglong2*)(src + 48);
        signed char* dr = Pl + row * 1024;
        *(unsigned long long*)(dr + ((seg +  0) ^ x)) = q0.x;
        *(unsigned long long*)(dr + ((seg +  8) ^ x)) = q0.y;
        *(unsigned long long*)(dr + ((seg + 16) ^ x)) = q1.x;
        *(unsigned long long*)(dr + ((seg + 24) ^ x)) = q1.y;
        *(unsigned long long*)(dr + ((seg + 32) ^ x)) = q2.x;
        *(unsigned long long*)(dr + ((seg + 40) ^ x)) = q2.y;
        *(unsigned long long*)(dr + ((seg + 48) ^ x)) = q3.x;
        *(unsigned long long*)(dr + ((seg + 56) ^ x)) = q3.y;
    }

    const int col = lane & 15;
    const int cc = h * 64 + wv * 16 + col;
    const signed char* bg = ivt + ((size_t)(b * 1024) + h * 64) * 1024;
    const int arow = lane & 15;
    const int xa = arow << 3;
    const int browo = (wv * 16 + col) * 128;
    const int xb = col << 3;
    const int kq = (lane >> 4) * 8;

    i32x4 acc = (i32x4){0, 0, 0, 0};
    for (int kc = 0; kc < 8; kc++) {
        __syncthreads();   // Pl ready (kc=0) / prev MFMA reads done
        {   // stage Bv[64][128] from IVT, coalesced, swizzled
            const int vrow = t >> 2, seg = (t & 3) * 32;
            const signed char* src = bg + (size_t)vrow * 1024 + kc * 128 + seg;
            ulonglong2 q0 = *(const ulonglong2*)(src);
            ulonglong2 q1 = *(const ulonglong2*)(src + 16);
            const int xv = (vrow & 15) << 3;
            char* drow = Bv + vrow * 128;
            *(unsigned long long*)(drow + ((seg +  0) ^ xv)) = q0.x;
            *(unsigned long long*)(drow + ((seg +  8) ^ xv)) = q0.y;
            *(unsigned long long*)(drow + ((seg + 16) ^ xv)) = q1.x;
            *(unsigned long long*)(drow + ((seg + 24) ^ xv)) = q1.y;
        }
        __syncthreads();
#pragma unroll
        for (int ks = 0; ks < 4; ks++) {
            const int ko = ks * 32 + kq;
            long a, bvv;
            __builtin_memcpy(&a,   Pl + arow * 1024 + ((kc * 128 + ko) ^ xa), 8);
            __builtin_memcpy(&bvv, Bv + browo + (ko ^ xb), 8);
            acc = __builtin_amdgcn_mfma_i32_16x16x32_i8(a, bvv, acc, 0, 0, 0);
        }
    }

    // epilogue (validated round 12): out = (S + 128*colsum) * s / 255
    const double sc = vs[b * 1024 + cc] * (1.0 / 255.0);
    const int cs = 128 * csum[b * 1024 + cc];
    const int rbase = qt * 16 + (lane >> 4) * 4;
#pragma unroll
    for (int r = 0; r < 4; r++) {
        int S = acc[r] + cs;
        double val = (double)S * sc;
        ctx[((size_t)(b * 1024) + rbase + r) * 1024 + cc] = f2b((float)val);
    }
}

// --- K5: out = ctx @ w_proj^T + b_proj, bf16 MFMA (post-cliff) ---------------
__global__ __launch_bounds__(256) void gemm_proj(const u16* __restrict__ ctx,
                                                 const u16* __restrict__ wproj,
                                                 const float* __restrict__ bproj,
                                                 float* __restrict__ out) {
    typedef __attribute__((ext_vector_type(8))) short short8;
    __shared__ u16 As[128 * 32], Bs[128 * 32];
    f32x4 acc[4][4];
#pragma unroll
    for (int i = 0; i < 4; i++)
#pragma unroll
        for (int j = 0; j < 4; j++) acc[i][j] = (f32x4){0.f, 0.f, 0.f, 0.f};

    const int t = threadIdx.x;
    const int lane = t & 63, w = t >> 6;
    const int wm = w >> 1, wn = w & 1;
    const int srow = t >> 2, scol = (t & 3) * 8;
    const int lm = lane & 15, lk = (lane >> 4) * 8;
    const int bm = blockIdx.y, bn = blockIdx.x;
    const u16* ap = ctx + (size_t)(bm * 128 + srow) * 1024 + scol;
    const u16* bp = wproj + (size_t)(bn * 128 + srow) * 1024 + scol;

    for (int k0 = 0; k0 < 1024; k0 += 32) {
        uint4 a0 = *(const uint4*)(ap + k0);
        uint4 a1 = *(const uint4*)(ap + (size_t)64 * 1024 + k0);
        uint4 b0 = *(const uint4*)(bp + k0);
        uint4 b1 = *(const uint4*)(bp + (size_t)64 * 1024 + k0);
        __syncthreads();
        *(uint4*)(As + srow * 32 + scol) = a0;
        *(uint4*)(As + (srow + 64) * 32 + scol) = a1;
        *(uint4*)(Bs + srow * 32 + scol) = b0;
        *(uint4*)(Bs + (srow + 64) * 32 + scol) = b1;
        __syncthreads();
        short8 af[4], bfr[4];
#pragma unroll
        for (int i = 0; i < 4; i++) {
            af[i]  = *(const short8*)(As + (wm * 64 + i * 16 + lm) * 32 + lk);
            bfr[i] = *(const short8*)(Bs + (wn * 64 + i * 16 + lm) * 32 + lk);
        }
#pragma unroll
        for (int mi = 0; mi < 4; mi++)
#pragma unroll
            for (int ni = 0; ni < 4; ni++)
                acc[mi][ni] = __builtin_amdgcn_mfma_f32_16x16x32_bf16(
                    af[mi], bfr[ni], acc[mi][ni], 0, 0, 0);
    }

    const int rbase = bm * 128 + wm * 64 + (lane >> 4) * 4;
    const int cbase = bn * 128 + wn * 64 + lm;
#pragma unroll
    for (int mi = 0; mi < 4; mi++)
#pragma unroll
        for (int ni = 0; ni < 4; ni++) {
            int col = cbase + ni * 16;
            float bias = bproj[col];
#pragma unroll
            for (int r = 0; r < 4; r++) {
                int row = rbase + mi * 16 + r;
                out[(size_t)row * 1024 + col] = acc[mi][ni][r] + bias;
            }
        }
}

// ---------------------------------------------------------------------------
extern "C" void kernel_launch(void* const* d_in, const int* in_sizes, int n_in,
                              void* d_out, int out_size, void* d_ws, size_t ws_size,
                              hipStream_t stream) {
    const float* x     = (const float*)d_in[0];
    const float* abias = (const float*)d_in[1];
    const float* wqkv  = (const float*)d_in[2];
    const float* qbias = (const float*)d_in[3];
    const float* vbias = (const float*)d_in[4];
    const float* wproj = (const float*)d_in[5];
    const float* bproj = (const float*)d_in[6];
    float* out = (float*)d_out;

    char* ws = (char*)d_ws;
    float*       qpre    = (float*)(ws + 0);
    float*       kpre    = (float*)(ws + 16777216);
    float*       vraw    = (float*)(ws + 33554432);
    u16*         wprojbf = (u16*)  (ws + 50331648);
    signed char* qint    = (signed char*)(ws + 52428800);
    int*         kT      = (int*)  (ws + 56623104);
    double*      qs      = (double*)(ws + 60817408);
    double*      ksT     = (double*)(ws + 61865984);
    double*      vs      = (double*)(ws + 62914560);
    float*       pmax    = (float*)(ws + 62947328);        // 1MB
    // aliases (live ranges disjoint, stream-ordered):
    u16*         ctx     = (u16*)(ws + 0);                 // over qpre
    signed char* ivt     = (signed char*)(ws + 16777216);  // over kpre (4MB)
    signed char* Pp      = (signed char*)(ws + 33554432);  // over vraw (per-b)
    int*         csum    = (int*)(ws + 62947328);          // over pmax (16KB)

    cvt_bf16w<<<1024, 256, 0, stream>>>(wprojbf, wproj, 1048576);
    gemm_qkv3<<<dim3(48, 32), 256, 0, stream>>>(x, wqkv, qbias, vbias,
                                                qpre, kpre, vraw);
    quant_qk<<<512, 256, 0, stream>>>(qpre, qint, qs);
    quant_k<<<512, 256, 0, stream>>>(kpre, kT, ksT);
    vmax_part<<<dim3(64, 4), 256, 0, stream>>>(vraw, pmax);
    vmax_final<<<16, 256, 0, stream>>>(pmax, vs);
    vquant_t<<<dim3(64, 4, 4), 256, 0, stream>>>(vraw, vs, ivt);
    colsum_k<<<16, 256, 0, stream>>>(ivt, csum);
    for (int b = 0; b < 4; b++) {
        attn_sc<<<dim3(256, 16), 256, 0, stream>>>(qint, kT, qs, ksT, abias, Pp, b);
        attn_av<<<dim3(64, 16), 256, 0, stream>>>(Pp, ivt, vs, csum, ctx, b);
    }
    gemm_proj<<<dim3(8, 32), 256, 0, stream>>>(ctx, wprojbf, bproj, out);
}

// Round 7
// 1339.278 us; speedup vs baseline: 1.6890x; 1.5751x over previous
//
#include <hip/hip_runtime.h>

// ---------------------------------------------------------------------------
// QuantSelfAttention on MI355X (gfx950).  B=4, L=1024, C=1024, H=16, D=64.
// Inputs f32, output f32.  Numerics (validated rounds 4-16, absmax 1.89e-3):
//   - qkv GEMM: fp16x2-split 3-pass MFMA + per-128-K-slab f64 accumulation
//   - q/k as int8 + per-32-group f64 scale; scores = exact int dots, f64 rescale
//   - softmax + round(a*255) in f64
//   - AV = exact integer GEMM via mfma_i32_16x16x32_i8:
//     out = (s_cc/255) * (sum_m (n_m-128)*iv_m + 128*colsum_cc), all int32.
// Round 17 (r15/r16 post-mortem: gfx950 launch_bounds law measured --
// arch-VGPR cap ~= 256/arg (unified VGPR/AGPR file halves the budget):
// arg=8 -> 32, arg=6 -> 40, both spilled sd[16].  r11's fused attn compiled
// to VGPR_Count=64 with this exact sc code -> the state fits in 64):
//   - attn_sc: __launch_bounds__(256, 4) -> cap 64, no spill, 32 waves/CU.
//   - attn_av: __launch_bounds__(256, 2) -> cap 128 (r16's 40 may have
//     quietly spilled too); LDS 24KB caps residency at 6 blocks/CU anyway.
//   - everything else unchanged.
//
// ws byte layout:
//   0         qpre   16MB f32   [aliased as ctx (bf16 8MB) after quant_qk]
//   16777216  kpre   16MB f32   [aliased as IVT (i8 4MB) after quant_k]
//   33554432  vraw   16MB f32   [aliased as Pp (i8 16MB, per-b) after vquant_t]
//   50331648  wprojbf 2MB u16
//   52428800  qint   4MB int8
//   56623104  kT     4MB int32 (64 bh x 16 j x 1024 m)
//   60817408  qs     1MB f64 (131072 groups)
//   61865984  ksT    1MB f64 (64 bh x 2 p x 1024 m)
//   62914560  vs     32KB f64 (4096)
//   62947328  pmax   1MB f32   [aliased as colsum (16KB i32) after vmax_final]
//   high-water 64.0MB (<67.3MB proven)
// ---------------------------------------------------------------------------

typedef unsigned short u16;
typedef unsigned int u32;
typedef __attribute__((ext_vector_type(8))) _Float16 half8;  // 8 f16 (4 VGPRs)
typedef __attribute__((ext_vector_type(4))) float f32x4;     // MFMA accumulator
typedef __attribute__((ext_vector_type(4))) int i32x4;       // i8-MFMA accumulator

__device__ __forceinline__ u16 f2b(float f) {   // f32 -> bf16 RNE
    u32 i;
    __builtin_memcpy(&i, &f, 4);
    return (u16)((i + 0x7FFFu + ((i >> 16) & 1u)) >> 16);
}

__device__ __forceinline__ void split16(float v, u16& hi, u16& lo) {
    _Float16 h = (_Float16)v;
    _Float16 l = (_Float16)(v - (float)h);
    __builtin_memcpy(&hi, &h, 2);
    __builtin_memcpy(&lo, &l, 2);
}

__device__ __forceinline__ int dot4(int a, int b, int c) {
#if __has_builtin(__builtin_amdgcn_sdot4)
    return __builtin_amdgcn_sdot4(a, b, c, false);
#else
    int r = c;
    r += ((a << 24) >> 24) * ((b << 24) >> 24);
    r += ((a << 16) >> 24) * ((b << 16) >> 24);
    r += ((a << 8) >> 24) * ((b << 8) >> 24);
    r += (a >> 24) * (b >> 24);
    return r;
#endif
}

// fast f64 exp for x <= 0 (scores are max-subtracted).  Cody-Waite range
// reduction + degree-10 Taylor (rel err ~2e-13) + exponent bit-add.
// exp(0) == 1.0 exactly.  x < -700 -> 0 (true value < 1e-304; a rounds to 0).
__device__ __forceinline__ double fexp(double x) {
    double kd = rint(x * 1.4426950408889634);
    double r = fma(kd, -6.93147180369123816490e-01, x);
    r = fma(kd, -1.90821492927058770002e-10, r);
    double p = 2.7557319223985888e-07;
    p = fma(p, r, 2.7557319223985890e-06);
    p = fma(p, r, 2.4801587301587302e-05);
    p = fma(p, r, 1.9841269841269841e-04);
    p = fma(p, r, 1.3888888888888889e-03);
    p = fma(p, r, 8.3333333333333333e-03);
    p = fma(p, r, 4.1666666666666664e-02);
    p = fma(p, r, 1.6666666666666666e-01);
    p = fma(p, r, 0.5);
    p = fma(p, r, 1.0);
    p = fma(p, r, 1.0);
    long long bits;
    __builtin_memcpy(&bits, &p, 8);
    bits += ((long long)kd) << 52;
    double e;
    __builtin_memcpy(&e, &bits, 8);
    return (x < -700.0) ? 0.0 : e;
}

// --- K0: w_proj f32 -> bf16 --------------------------------------------------
__global__ __launch_bounds__(256) void cvt_bf16w(u16* __restrict__ dst,
                                                 const float* __restrict__ src, int n) {
    int i = (blockIdx.x * 256 + threadIdx.x) * 4;
    if (i + 3 < n) {
        float4 v = *(const float4*)(src + i);
        ushort4 o;
        o.x = f2b(v.x); o.y = f2b(v.y); o.z = f2b(v.z); o.w = f2b(v.w);
        *(ushort4*)(dst + i) = o;
    }
}

// ---------------------------------------------------------------------------
// K1: qkv = x @ w_qkv^T + bias, fp16x2-split 3-pass MFMA, f64 slab accumulate.
// 128x64 output blocks (grid 48 x 32).  Per-output K-order identical to the
// round-4..16 passing versions -> bit-identical results.
// ---------------------------------------------------------------------------
__global__ __launch_bounds__(256) void gemm_qkv3(const float* __restrict__ A,
                                                 const float* __restrict__ Bm,
                                                 const float* __restrict__ qbias,
                                                 const float* __restrict__ vbias,
                                                 float* __restrict__ qws,
                                                 float* __restrict__ kws,
                                                 float* __restrict__ vws) {
    __shared__ u16 Ah[128 * 32], Al[128 * 32], Bh[64 * 32], Bl[64 * 32];
    const int t = threadIdx.x;
    const int lane = t & 63, w = t >> 6;
    const int srow = t >> 2, scol = (t & 3) * 8;
    const int lm = lane & 15, lk = (lane >> 4) * 8;
    const int bm = blockIdx.y, bn = blockIdx.x;

    const float* ap = A + (size_t)(bm * 128 + srow) * 1024 + scol;
    const float* bp = Bm + (size_t)(bn * 64 + srow) * 1024 + scol;

    double dacc[2][4][4];
#pragma unroll
    for (int i = 0; i < 2; i++)
#pragma unroll
        for (int j = 0; j < 4; j++)
#pragma unroll
            for (int r = 0; r < 4; r++) dacc[i][j][r] = 0.0;

    for (int slab = 0; slab < 8; slab++) {
        f32x4 acc[2][4];
#pragma unroll
        for (int i = 0; i < 2; i++)
#pragma unroll
            for (int j = 0; j < 4; j++) acc[i][j] = (f32x4){0.f, 0.f, 0.f, 0.f};

        for (int kc = 0; kc < 4; kc++) {
            const int k0 = slab * 128 + kc * 32;
            float vreg[3][8];
#pragma unroll
            for (int e = 0; e < 3; e++) {
                const float* src = (e < 2) ? (ap + e * (size_t)64 * 1024 + k0)
                                           : (bp + k0);
                float4 v0 = *(const float4*)(src);
                float4 v1 = *(const float4*)(src + 4);
                vreg[e][0] = v0.x; vreg[e][1] = v0.y; vreg[e][2] = v0.z; vreg[e][3] = v0.w;
                vreg[e][4] = v1.x; vreg[e][5] = v1.y; vreg[e][6] = v1.z; vreg[e][7] = v1.w;
            }
            __syncthreads();
#pragma unroll
            for (int e = 0; e < 3; e++) {
                union { u16 us[8]; uint4 v; } ph, pl;
#pragma unroll
                for (int j = 0; j < 8; j++) split16(vreg[e][j], ph.us[j], pl.us[j]);
                u16* dh = (e < 2) ? Ah : Bh;
                u16* dl = (e < 2) ? Al : Bl;
                int row = (e < 2) ? (srow + e * 64) : srow;
                *(uint4*)(dh + row * 32 + scol) = ph.v;
                *(uint4*)(dl + row * 32 + scol) = pl.v;
            }
            __syncthreads();

            half8 fah[2], fal[2], fbh[4], fbl[4];
#pragma unroll
            for (int i = 0; i < 2; i++) {
                int ra = (w * 32 + i * 16 + lm) * 32 + lk;
                fah[i] = *(const half8*)(Ah + ra);
                fal[i] = *(const half8*)(Al + ra);
            }
#pragma unroll
            for (int i = 0; i < 4; i++) {
                int rb = (i * 16 + lm) * 32 + lk;
                fbh[i] = *(const half8*)(Bh + rb);
                fbl[i] = *(const half8*)(Bl + rb);
            }
#pragma unroll
            for (int mi = 0; mi < 2; mi++)
#pragma unroll
                for (int ni = 0; ni < 4; ni++) {
                    acc[mi][ni] = __builtin_amdgcn_mfma_f32_16x16x32_f16(
                        fal[mi], fbh[ni], acc[mi][ni], 0, 0, 0);
                    acc[mi][ni] = __builtin_amdgcn_mfma_f32_16x16x32_f16(
                        fah[mi], fbl[ni], acc[mi][ni], 0, 0, 0);
                    acc[mi][ni] = __builtin_amdgcn_mfma_f32_16x16x32_f16(
                        fah[mi], fbh[ni], acc[mi][ni], 0, 0, 0);
                }
        }
#pragma unroll
        for (int i = 0; i < 2; i++)
#pragma unroll
            for (int j = 0; j < 4; j++)
#pragma unroll
                for (int r = 0; r < 4; r++) dacc[i][j][r] += (double)acc[i][j][r];
    }

    const int rbase = bm * 128 + w * 32 + (lane >> 4) * 4;
    const int cbase = bn * 64 + lm;
#pragma unroll
    for (int mi = 0; mi < 2; mi++)
#pragma unroll
        for (int ni = 0; ni < 4; ni++) {
            int col = cbase + ni * 16;
            int sel = col >> 10, cc = col & 1023;
            double bias = (sel == 0) ? (double)qbias[cc]
                        : ((sel == 2) ? (double)vbias[cc] : 0.0);
            float* dst = (sel == 0) ? qws : ((sel == 1) ? kws : vws);
#pragma unroll
            for (int r = 0; r < 4; r++) {
                int row = rbase + mi * 16 + r;
                dst[(size_t)row * 1024 + cc] = (float)(dacc[mi][ni][r] + bias);
            }
        }
}

// --- K2a: per-32-group quant of q -> int8 (row-major) + f64 scale ------------
__global__ __launch_bounds__(256) void quant_qk(const float* __restrict__ pre,
                                                signed char* __restrict__ qout,
                                                double* __restrict__ sout) {
    size_t g = (size_t)blockIdx.x * 256 + threadIdx.x;   // 131072 groups
    const float* p = pre + g * 32;
    float v[32];
    float amax = 0.f;
#pragma unroll
    for (int i = 0; i < 8; i++) {
        float4 q4 = ((const float4*)p)[i];
        v[i * 4 + 0] = q4.x; v[i * 4 + 1] = q4.y; v[i * 4 + 2] = q4.z; v[i * 4 + 3] = q4.w;
        amax = fmaxf(amax, fmaxf(fmaxf(fabsf(q4.x), fabsf(q4.y)),
                                 fmaxf(fabsf(q4.z), fabsf(q4.w))));
    }
    double s = fmax((double)amax / 127.0, 1e-8);
    sout[g] = s;
    int pk[8];
#pragma unroll
    for (int i = 0; i < 8; i++) {
        int b0 = (int)fmin(fmax(rint((double)v[i * 4 + 0] / s), -128.0), 127.0);
        int b1 = (int)fmin(fmax(rint((double)v[i * 4 + 1] / s), -128.0), 127.0);
        int b2 = (int)fmin(fmax(rint((double)v[i * 4 + 2] / s), -128.0), 127.0);
        int b3 = (int)fmin(fmax(rint((double)v[i * 4 + 3] / s), -128.0), 127.0);
        pk[i] = (b0 & 255) | ((b1 & 255) << 8) | ((b2 & 255) << 16) | ((b3 & 255) << 24);
    }
    int4* d = (int4*)(qout + g * 32);
    d[0] = make_int4(pk[0], pk[1], pk[2], pk[3]);
    d[1] = make_int4(pk[4], pk[5], pk[6], pk[7]);
}

// --- K2b: per-32-group quant of k -> TRANSPOSED j-major layout ---------------
__global__ __launch_bounds__(256) void quant_k(const float* __restrict__ pre,
                                               int* __restrict__ kT,
                                               double* __restrict__ ksT) {
    size_t g = (size_t)blockIdx.x * 256 + threadIdx.x;   // 131072 groups
    const float* p = pre + g * 32;
    float v[32];
    float amax = 0.f;
#pragma unroll
    for (int i = 0; i < 8; i++) {
        float4 q4 = ((const float4*)p)[i];
        v[i * 4 + 0] = q4.x; v[i * 4 + 1] = q4.y; v[i * 4 + 2] = q4.z; v[i * 4 + 3] = q4.w;
        amax = fmaxf(amax, fmaxf(fmaxf(fabsf(q4.x), fabsf(q4.y)),
                                 fmaxf(fabsf(q4.z), fabsf(q4.w))));
    }
    double s = fmax((double)amax / 127.0, 1e-8);
    int pk[8];
#pragma unroll
    for (int i = 0; i < 8; i++) {
        int b0 = (int)fmin(fmax(rint((double)v[i * 4 + 0] / s), -128.0), 127.0);
        int b1 = (int)fmin(fmax(rint((double)v[i * 4 + 1] / s), -128.0), 127.0);
        int b2 = (int)fmin(fmax(rint((double)v[i * 4 + 2] / s), -128.0), 127.0);
        int b3 = (int)fmin(fmax(rint((double)v[i * 4 + 3] / s), -128.0), 127.0);
        pk[i] = (b0 & 255) | ((b1 & 255) << 8) | ((b2 & 255) << 16) | ((b3 & 255) << 24);
    }
    const int m = (int)((g >> 5) & 1023);
    const int b = (int)(g >> 15);
    const int sub = (int)(g & 31);
    const int h = sub >> 1, pp = sub & 1;
    const int bh = b * 16 + h;
    int* dst = kT + ((size_t)bh * 16 + pp * 8) * 1024 + m;
#pragma unroll
    for (int i = 0; i < 8; i++) dst[i * 1024] = pk[i];
    ksT[((size_t)bh * 2 + pp) * 1024 + m] = s;
}

// --- K3a: partial max|v| over 16-row L-chunks (256 blocks) -------------------
__global__ __launch_bounds__(256) void vmax_part(const float* __restrict__ vws,
                                                 float* __restrict__ pmax) {
    const int lc = blockIdx.x, b = blockIdx.y, t = threadIdx.x;
#pragma unroll
    for (int j = 0; j < 4; j++) {
        int cc = t + j * 256;
        float mx = 0.f;
        for (int l = 0; l < 16; l++)
            mx = fmaxf(mx, fabsf(vws[((size_t)(b * 1024 + lc * 16 + l)) * 1024 + cc]));
        pmax[(size_t)(b * 64 + lc) * 1024 + cc] = mx;
    }
}

// --- K3b: reduce 64 partials -> vs[b*1024+cc] = max(amax/127, eps) f64 -------
__global__ __launch_bounds__(256) void vmax_final(const float* __restrict__ pmax,
                                                  double* __restrict__ vs) {
    int id = blockIdx.x * 256 + threadIdx.x;   // 4096
    int b = id >> 10, cc = id & 1023;
    float mx = 0.f;
    for (int p = 0; p < 64; p++)
        mx = fmaxf(mx, pmax[(size_t)(b * 64 + p) * 1024 + cc]);
    vs[id] = fmax((double)mx / 127.0, 1e-8);
}

// --- K3c: gather-transpose quant v -> IVT[b][cc][m] (f64 decisions) ----------
__global__ __launch_bounds__(256) void vquant_t(const float* __restrict__ vraw,
                                                const double* __restrict__ vs,
                                                signed char* __restrict__ ivt) {
    const int mt = blockIdx.x;            // 0..63  (16-m strip)
    const int ccg = blockIdx.y;           // 0..3   (256-cc group)
    const int b = blockIdx.z;             // 0..3
    const int cc = ccg * 256 + threadIdx.x;
    const double s = vs[b * 1024 + cc];
    const float* src = vraw + ((size_t)(b * 1024) + mt * 16) * 1024 + cc;
    signed char bytes[16];
#pragma unroll
    for (int i = 0; i < 16; i++) {
        float v = src[(size_t)i * 1024];
        bytes[i] = (signed char)(int)fmin(fmax(rint((double)v / s), -128.0), 127.0);
    }
    int4 pk;
    __builtin_memcpy(&pk, bytes, 16);
    *(int4*)(ivt + ((size_t)(b * 1024) + cc) * 1024 + mt * 16) = pk;
}

// --- K3d: colsum[b*1024+cc] = sum_m iv[m][cc] (exact i32) --------------------
__global__ __launch_bounds__(256) void colsum_k(const signed char* __restrict__ ivt,
                                                int* __restrict__ csum) {
    int id = blockIdx.x * 256 + threadIdx.x;   // 4096
    const int4* p = (const int4*)(ivt + (size_t)id * 1024);
    int s = 0;
    for (int i = 0; i < 64; i++) {
        int4 w = p[i];
        s = dot4(w.x, 0x01010101, s);
        s = dot4(w.y, 0x01010101, s);
        s = dot4(w.z, 0x01010101, s);
        s = dot4(w.w, 0x01010101, s);
    }
    csum[id] = s;
}

// ---------------------------------------------------------------------------
// K4a: scores + softmax + n (validated).  One wave per query row, 20KB LDS.
// __launch_bounds__(256, 4): gfx950 law arch-VGPR cap = 256/arg -> 64.
// r11's fused attn compiled to exactly 64 VGPR with this same sc state ->
// no spill.  2048/64 = 32 waves/CU capacity; LDS allows 8 blocks = 32 waves.
// ---------------------------------------------------------------------------
__global__ __launch_bounds__(256, 4) void attn_sc(const signed char* __restrict__ qint,
                                                  const int* __restrict__ kT,
                                                  const double* __restrict__ qs,
                                                  const double* __restrict__ ksT,
                                                  const float* __restrict__ abias,
                                                  signed char* __restrict__ Pp,
                                                  int b) {
    __shared__ int    kTs[16][256];        // 16 KB
    __shared__ double ks0s[256], ks1s[256];//  4 KB
    const int t = threadIdx.x;
    const int wv = t >> 6, lane = t & 63;
    const int qt = blockIdx.x, h = blockIdx.y;
    const int row = qt * 4 + wv;
    const size_t qrow = (size_t)(b * 1024 + row);
    const int bh = b * 16 + h;

    const int* qv = (const int*)(qint + qrow * 1024 + h * 64);
    int qd[16];
#pragma unroll
    for (int j = 0; j < 4; j++) {
        int4 tmp = ((const int4*)qv)[j];
        qd[j * 4 + 0] = tmp.x; qd[j * 4 + 1] = tmp.y;
        qd[j * 4 + 2] = tmp.z; qd[j * 4 + 3] = tmp.w;
    }
    const double sq0 = qs[qrow * 32 + 2 * h], sq1 = qs[qrow * 32 + 2 * h + 1];
    const int* kTg = kT + (size_t)bh * 16384;
    const double* ks0g = ksT + (size_t)(bh * 2) * 1024;
    const double* ks1g = ksT + (size_t)(bh * 2 + 1) * 1024;
    const float* ab = abias + (size_t)row * 1024;

    double sd[16];
    for (int c = 0; c < 4; c++) {
        if (c) __syncthreads();
#pragma unroll
        for (int r = 0; r < 4; r++) {
            const int j = wv * 4 + r;
            int4 val = *(const int4*)(kTg + (size_t)j * 1024 + c * 256 + 4 * lane);
            *(int4*)(&kTs[j][4 * lane]) = val;
        }
        ks0s[t] = ks0g[c * 256 + t];
        ks1s[t] = ks1g[c * 256 + t];
        __syncthreads();
#pragma unroll
        for (int s = 0; s < 4; s++) {
            const int ml = s * 64 + lane;
            int I0 = 0, I1 = 0;
#pragma unroll
            for (int j = 0; j < 8; j++)  I0 = dot4(qd[j], kTs[j][ml], I0);
#pragma unroll
            for (int j = 8; j < 16; j++) I1 = dot4(qd[j], kTs[j][ml], I1);
            sd[c * 4 + s] = 0.125 * (sq0 * ks0s[ml] * (double)I0
                                   + sq1 * ks1s[ml] * (double)I1)
                          + (double)ab[c * 256 + ml];
        }
    }

    // softmax (f64): custom exp, single reciprocal
    double mx = sd[0];
#pragma unroll
    for (int it = 1; it < 16; it++) mx = fmax(mx, sd[it]);
#pragma unroll
    for (int off = 1; off < 64; off <<= 1) mx = fmax(mx, __shfl_xor(mx, off));
    double sum = 0.0;
#pragma unroll
    for (int it = 0; it < 16; it++) {
        double e = fexp(sd[it] - mx);
        sd[it] = e;
        sum += e;
    }
#pragma unroll
    for (int off = 1; off < 64; off <<= 1) sum += __shfl_xor(sum, off);
    const double inv = 1.0 / sum;

    // n = clamp(round(a*255),0,255); store n-128 as i8 (coalesced 64B/wave)
    signed char* prow = Pp + ((size_t)h * 1024 + row) * 1024;
#pragma unroll
    for (int it = 0; it < 16; it++) {
        double a = sd[it] * inv;
        double nd = fmin(fmax(rint(a * 255.0), 0.0), 255.0);
        int ni = (int)nd;
        prow[it * 64 + lane] = (signed char)(ni - 128);
    }
}

// ---------------------------------------------------------------------------
// K4b: AV as exact-int i8 MFMA (validated r13/r14).  Block = (qt,h): stage P
// tile 16x1024 from Pp (coalesced, (row<<3) XOR swizzle); V chunks from IVT
// with (vrow&15)<<3 swizzle; 32 MFMAs; epilogue (S+128*colsum)*s/255.
// LDS 24KB -> 6 blocks/CU.  launch_bounds(256,2) -> arch-VGPR cap 128
// (gfx950 law 256/arg): no spill risk, LDS caps residency anyway.
// ---------------------------------------------------------------------------
__global__ __launch_bounds__(256, 2) void attn_av(const signed char* __restrict__ Pp,
                                                  const signed char* __restrict__ ivt,
                                                  const double* __restrict__ vs,
                                                  const int* __restrict__ csum,
                                                  u16* __restrict__ ctx,
                                                  int b) {
    __shared__ __align__(16) char smem[24576];
    signed char* Pl = (signed char*)smem;               // [16][1024] swizzled
    char*        Bv = smem + 16384;                     // [64][128]  swizzled
    const int t = threadIdx.x;
    const int wv = t >> 6, lane = t & 63;
    const int qt = blockIdx.x, h = blockIdx.y;

    // stage P tile (16 rows x 1024B), coalesced 64B/thread, 8B-XOR swizzle
    {
        const int row = t >> 4, seg = (t & 15) * 64;
        const signed char* src = Pp + ((size_t)h * 1024 + qt * 16 + row) * 1024 + seg;
        const int x = row << 3;
        ulonglong2 q0 = *(const ulonglong2*)(src);
        ulonglong2 q1 = *(const ulonglong2*)(src + 16);
        ulonglong2 q2 = *(const ulonglong2*)(src + 32);
        ulonglong2 q3 = *(const ulonglong2*)(src + 48);
        signed char* dr = Pl + row * 1024;
        *(unsigned long long*)(dr + ((seg +  0) ^ x)) = q0.x;
        *(unsigned long long*)(dr + ((seg +  8) ^ x)) = q0.y;
        *(unsigned long long*)(dr + ((seg + 16) ^ x)) = q1.x;
        *(unsigned long long*)(dr + ((seg + 24) ^ x)) = q1.y;
        *(unsigned long long*)(dr + ((seg + 32) ^ x)) = q2.x;
        *(unsigned long long*)(dr + ((seg + 40) ^ x)) = q2.y;
        *(unsigned long long*)(dr + ((seg + 48) ^ x)) = q3.x;
        *(unsigned long long*)(dr + ((seg + 56) ^ x)) = q3.y;
    }

    const int col = lane & 15;
    const int cc = h * 64 + wv * 16 + col;
    const signed char* bg = ivt + ((size_t)(b * 1024) + h * 64) * 1024;
    const int arow = lane & 15;
    const int xa = arow << 3;
    const int browo = (wv * 16 + col) * 128;
    const int xb = col << 3;
    const int kq = (lane >> 4) * 8;

    i32x4 acc = (i32x4){0, 0, 0, 0};
    for (int kc = 0; kc < 8; kc++) {
        __syncthreads();   // Pl ready (kc=0) / prev MFMA reads done
        {   // stage Bv[64][128] from IVT, coalesced, swizzled
            const int vrow = t >> 2, seg = (t & 3) * 32;
            const signed char* src = bg + (size_t)vrow * 1024 + kc * 128 + seg;
            ulonglong2 q0 = *(const ulonglong2*)(src);
            ulonglong2 q1 = *(const ulonglong2*)(src + 16);
            const int xv = (vrow & 15) << 3;
            char* drow = Bv + vrow * 128;
            *(unsigned long long*)(drow + ((seg +  0) ^ xv)) = q0.x;
            *(unsigned long long*)(drow + ((seg +  8) ^ xv)) = q0.y;
            *(unsigned long long*)(drow + ((seg + 16) ^ xv)) = q1.x;
            *(unsigned long long*)(drow + ((seg + 24) ^ xv)) = q1.y;
        }
        __syncthreads();
#pragma unroll
        for (int ks = 0; ks < 4; ks++) {
            const int ko = ks * 32 + kq;
            long a, bvv;
            __builtin_memcpy(&a,   Pl + arow * 1024 + ((kc * 128 + ko) ^ xa), 8);
            __builtin_memcpy(&bvv, Bv + browo + (ko ^ xb), 8);
            acc = __builtin_amdgcn_mfma_i32_16x16x32_i8(a, bvv, acc, 0, 0, 0);
        }
    }

    // epilogue (validated round 12): out = (S + 128*colsum) * s / 255
    const double sc = vs[b * 1024 + cc] * (1.0 / 255.0);
    const int cs = 128 * csum[b * 1024 + cc];
    const int rbase = qt * 16 + (lane >> 4) * 4;
#pragma unroll
    for (int r = 0; r < 4; r++) {
        int S = acc[r] + cs;
        double val = (double)S * sc;
        ctx[((size_t)(b * 1024) + rbase + r) * 1024 + cc] = f2b((float)val);
    }
}

// --- K5: out = ctx @ w_proj^T + b_proj, bf16 MFMA (post-cliff) ---------------
__global__ __launch_bounds__(256) void gemm_proj(const u16* __restrict__ ctx,
                                                 const u16* __restrict__ wproj,
                                                 const float* __restrict__ bproj,
                                                 float* __restrict__ out) {
    typedef __attribute__((ext_vector_type(8))) short short8;
    __shared__ u16 As[128 * 32], Bs[128 * 32];
    f32x4 acc[4][4];
#pragma unroll
    for (int i = 0; i < 4; i++)
#pragma unroll
        for (int j = 0; j < 4; j++) acc[i][j] = (f32x4){0.f, 0.f, 0.f, 0.f};

    const int t = threadIdx.x;
    const int lane = t & 63, w = t >> 6;
    const int wm = w >> 1, wn = w & 1;
    const int srow = t >> 2, scol = (t & 3) * 8;
    const int lm = lane & 15, lk = (lane >> 4) * 8;
    const int bm = blockIdx.y, bn = blockIdx.x;
    const u16* ap = ctx + (size_t)(bm * 128 + srow) * 1024 + scol;
    const u16* bp = wproj + (size_t)(bn * 128 + srow) * 1024 + scol;

    for (int k0 = 0; k0 < 1024; k0 += 32) {
        uint4 a0 = *(const uint4*)(ap + k0);
        uint4 a1 = *(const uint4*)(ap + (size_t)64 * 1024 + k0);
        uint4 b0 = *(const uint4*)(bp + k0);
        uint4 b1 = *(const uint4*)(bp + (size_t)64 * 1024 + k0);
        __syncthreads();
        *(uint4*)(As + srow * 32 + scol) = a0;
        *(uint4*)(As + (srow + 64) * 32 + scol) = a1;
        *(uint4*)(Bs + srow * 32 + scol) = b0;
        *(uint4*)(Bs + (srow + 64) * 32 + scol) = b1;
        __syncthreads();
        short8 af[4], bfr[4];
#pragma unroll
        for (int i = 0; i < 4; i++) {
            af[i]  = *(const short8*)(As + (wm * 64 + i * 16 + lm) * 32 + lk);
            bfr[i] = *(const short8*)(Bs + (wn * 64 + i * 16 + lm) * 32 + lk);
        }
#pragma unroll
        for (int mi = 0; mi < 4; mi++)
#pragma unroll
            for (int ni = 0; ni < 4; ni++)
                acc[mi][ni] = __builtin_amdgcn_mfma_f32_16x16x32_bf16(
                    af[mi], bfr[ni], acc[mi][ni], 0, 0, 0);
    }

    const int rbase = bm * 128 + wm * 64 + (lane >> 4) * 4;
    const int cbase = bn * 128 + wn * 64 + lm;
#pragma unroll
    for (int mi = 0; mi < 4; mi++)
#pragma unroll
        for (int ni = 0; ni < 4; ni++) {
            int col = cbase + ni * 16;
            float bias = bproj[col];
#pragma unroll
            for (int r = 0; r < 4; r++) {
                int row = rbase + mi * 16 + r;
                out[(size_t)row * 1024 + col] = acc[mi][ni][r] + bias;
            }
        }
}

// ---------------------------------------------------------------------------
extern "C" void kernel_launch(void* const* d_in, const int* in_sizes, int n_in,
                              void* d_out, int out_size, void* d_ws, size_t ws_size,
                              hipStream_t stream) {
    const float* x     = (const float*)d_in[0];
    const float* abias = (const float*)d_in[1];
    const float* wqkv  = (const float*)d_in[2];
    const float* qbias = (const float*)d_in[3];
    const float* vbias = (const float*)d_in[4];
    const float* wproj = (const float*)d_in[5];
    const float* bproj = (const float*)d_in[6];
    float* out = (float*)d_out;

    char* ws = (char*)d_ws;
    float*       qpre    = (float*)(ws + 0);
    float*       kpre    = (float*)(ws + 16777216);
    float*       vraw    = (float*)(ws + 33554432);
    u16*         wprojbf = (u16*)  (ws + 50331648);
    signed char* qint    = (signed char*)(ws + 52428800);
    int*         kT      = (int*)  (ws + 56623104);
    double*      qs      = (double*)(ws + 60817408);
    double*      ksT     = (double*)(ws + 61865984);
    double*      vs      = (double*)(ws + 62914560);
    float*       pmax    = (float*)(ws + 62947328);        // 1MB
    // aliases (live ranges disjoint, stream-ordered):
    u16*         ctx     = (u16*)(ws + 0);                 // over qpre
    signed char* ivt     = (signed char*)(ws + 16777216);  // over kpre (4MB)
    signed char* Pp      = (signed char*)(ws + 33554432);  // over vraw (per-b)
    int*         csum    = (int*)(ws + 62947328);          // over pmax (16KB)

    cvt_bf16w<<<1024, 256, 0, stream>>>(wprojbf, wproj, 1048576);
    gemm_qkv3<<<dim3(48, 32), 256, 0, stream>>>(x, wqkv, qbias, vbias,
                                                qpre, kpre, vraw);
    quant_qk<<<512, 256, 0, stream>>>(qpre, qint, qs);
    quant_k<<<512, 256, 0, stream>>>(kpre, kT, ksT);
    vmax_part<<<dim3(64, 4), 256, 0, stream>>>(vraw, pmax);
    vmax_final<<<16, 256, 0, stream>>>(pmax, vs);
    vquant_t<<<dim3(64, 4, 4), 256, 0, stream>>>(vraw, vs, ivt);
    colsum_k<<<16, 256, 0, stream>>>(ivt, csum);
    for (int b = 0; b < 4; b++) {
        attn_sc<<<dim3(256, 16), 256, 0, stream>>>(qint, kT, qs, ksT, abias, Pp, b);
        attn_av<<<dim3(64, 16), 256, 0, stream>>>(Pp, ivt, vs, csum, ctx, b);
    }
    gemm_proj<<<dim3(8, 32), 256, 0, stream>>>(ctx, wprojbf, bproj, out);
}

// Round 8
// 518.059 us; speedup vs baseline: 4.3664x; 2.5852x over previous
//
#include <hip/hip_runtime.h>

// ---------------------------------------------------------------------------
// QuantSelfAttention on MI355X (gfx950).  B=4, L=1024, C=1024, H=16, D=64.
// Inputs f32, output f32.  Numerics (validated rounds 4-10, absmax 1.89e-3):
//   - qkv GEMM: fp16x2-split 3-pass MFMA + per-128-K-slab f64 accumulation
//   - q/k as int8 + per-32-group f64 scale; scores = exact int dots, f64 rescale
//   - softmax + round(a*255) in f64;  AV + proj GEMM post-cliff (f32/bf16)
// Round 18: REVERT to the round-11 state (best measured: 524.6/527.4 us).
// The r12-r17 arc proved: (a) exact-int i8-MFMA AV is numerically valid but
// (b) the standalone attn_sc kernel needs ~150 VGPR (measured spill ladder:
// cap 32/40/64 -> 556/496/393 MB spill-fetch) -> either spill-bound or
// occupancy-bound in every reachable compilation regime, always losing to
// this fused kernel (VGPR 64, no spill, VALUBusy 74%).  gfx950 law learned:
// launch_bounds arg caps arch-VGPRs at ~256/arg; r11's 64-VGPR allocation
// of the sc phase exists only inside this fused kernel's regalloc context.
//
// ws byte layout:
//   0         qpre   16MB f32   [aliased as ctx (bf16 8MB) after quant]
//   16777216  kpre   16MB f32
//   33554432  vfq    16MB f32
//   50331648  wprojbf 2MB u16
//   52428800  qint   4MB int8
//   56623104  kT     4MB int32 (64 bh x 16 j x 1024 m)
//   60817408  qs     1MB f64 (131072 groups)
//   61865984  ksT    1MB f64 (64 bh x 2 p x 1024 m)
//   62914560  vs     32KB f64 (4096)
//   62947328  pmax   1MB f32 (262144)   -> high-water 64.0MB (<67.3MB proven)
// ---------------------------------------------------------------------------

typedef unsigned short u16;
typedef unsigned int u32;
typedef __attribute__((ext_vector_type(8))) _Float16 half8;  // 8 f16 (4 VGPRs)
typedef __attribute__((ext_vector_type(4))) float f32x4;     // MFMA accumulator

__device__ __forceinline__ u16 f2b(float f) {   // f32 -> bf16 RNE
    u32 i;
    __builtin_memcpy(&i, &f, 4);
    return (u16)((i + 0x7FFFu + ((i >> 16) & 1u)) >> 16);
}

__device__ __forceinline__ void split16(float v, u16& hi, u16& lo) {
    _Float16 h = (_Float16)v;
    _Float16 l = (_Float16)(v - (float)h);
    __builtin_memcpy(&hi, &h, 2);
    __builtin_memcpy(&lo, &l, 2);
}

__device__ __forceinline__ int dot4(int a, int b, int c) {
#if __has_builtin(__builtin_amdgcn_sdot4)
    return __builtin_amdgcn_sdot4(a, b, c, false);
#else
    int r = c;
    r += ((a << 24) >> 24) * ((b << 24) >> 24);
    r += ((a << 16) >> 24) * ((b << 16) >> 24);
    r += ((a << 8) >> 24) * ((b << 8) >> 24);
    r += (a >> 24) * (b >> 24);
    return r;
#endif
}

// fast f64 exp for x <= 0 (scores are max-subtracted).  Cody-Waite range
// reduction + degree-10 Taylor (rel err ~2e-13) + exponent bit-add.
// exp(0) == 1.0 exactly.  x < -700 -> 0 (true value < 1e-304; a rounds to 0).
__device__ __forceinline__ double fexp(double x) {
    double kd = rint(x * 1.4426950408889634);
    double r = fma(kd, -6.93147180369123816490e-01, x);
    r = fma(kd, -1.90821492927058770002e-10, r);
    double p = 2.7557319223985888e-07;
    p = fma(p, r, 2.7557319223985890e-06);
    p = fma(p, r, 2.4801587301587302e-05);
    p = fma(p, r, 1.9841269841269841e-04);
    p = fma(p, r, 1.3888888888888889e-03);
    p = fma(p, r, 8.3333333333333333e-03);
    p = fma(p, r, 4.1666666666666664e-02);
    p = fma(p, r, 1.6666666666666666e-01);
    p = fma(p, r, 0.5);
    p = fma(p, r, 1.0);
    p = fma(p, r, 1.0);
    long long bits;
    __builtin_memcpy(&bits, &p, 8);
    bits += ((long long)kd) << 52;
    double e;
    __builtin_memcpy(&e, &bits, 8);
    return (x < -700.0) ? 0.0 : e;
}

// --- K0: w_proj f32 -> bf16 --------------------------------------------------
__global__ __launch_bounds__(256) void cvt_bf16w(u16* __restrict__ dst,
                                                 const float* __restrict__ src, int n) {
    int i = (blockIdx.x * 256 + threadIdx.x) * 4;
    if (i + 3 < n) {
        float4 v = *(const float4*)(src + i);
        ushort4 o;
        o.x = f2b(v.x); o.y = f2b(v.y); o.z = f2b(v.z); o.w = f2b(v.w);
        *(ushort4*)(dst + i) = o;
    }
}

// ---------------------------------------------------------------------------
// K1: qkv = x @ w_qkv^T + bias, fp16x2-split 3-pass MFMA, f64 slab accumulate.
// 128x64 output blocks (grid 48 x 32).  Wave w: rows w*32..w*32+31,
// all 64 cols (2x4 frags of 16x16x32).  Per-output K-order identical to the
// round-4..9 passing versions -> bit-identical results.
// ---------------------------------------------------------------------------
__global__ __launch_bounds__(256) void gemm_qkv3(const float* __restrict__ A,
                                                 const float* __restrict__ Bm,
                                                 const float* __restrict__ qbias,
                                                 const float* __restrict__ vbias,
                                                 float* __restrict__ qws,
                                                 float* __restrict__ kws,
                                                 float* __restrict__ vws) {
    __shared__ u16 Ah[128 * 32], Al[128 * 32], Bh[64 * 32], Bl[64 * 32];
    const int t = threadIdx.x;
    const int lane = t & 63, w = t >> 6;
    const int srow = t >> 2, scol = (t & 3) * 8;
    const int lm = lane & 15, lk = (lane >> 4) * 8;
    const int bm = blockIdx.y, bn = blockIdx.x;

    const float* ap = A + (size_t)(bm * 128 + srow) * 1024 + scol;
    const float* bp = Bm + (size_t)(bn * 64 + srow) * 1024 + scol;

    double dacc[2][4][4];
#pragma unroll
    for (int i = 0; i < 2; i++)
#pragma unroll
        for (int j = 0; j < 4; j++)
#pragma unroll
            for (int r = 0; r < 4; r++) dacc[i][j][r] = 0.0;

    for (int slab = 0; slab < 8; slab++) {
        f32x4 acc[2][4];
#pragma unroll
        for (int i = 0; i < 2; i++)
#pragma unroll
            for (int j = 0; j < 4; j++) acc[i][j] = (f32x4){0.f, 0.f, 0.f, 0.f};

        for (int kc = 0; kc < 4; kc++) {
            const int k0 = slab * 128 + kc * 32;
            float vreg[3][8];
#pragma unroll
            for (int e = 0; e < 3; e++) {
                const float* src = (e < 2) ? (ap + e * (size_t)64 * 1024 + k0)
                                           : (bp + k0);
                float4 v0 = *(const float4*)(src);
                float4 v1 = *(const float4*)(src + 4);
                vreg[e][0] = v0.x; vreg[e][1] = v0.y; vreg[e][2] = v0.z; vreg[e][3] = v0.w;
                vreg[e][4] = v1.x; vreg[e][5] = v1.y; vreg[e][6] = v1.z; vreg[e][7] = v1.w;
            }
            __syncthreads();
#pragma unroll
            for (int e = 0; e < 3; e++) {
                union { u16 us[8]; uint4 v; } ph, pl;
#pragma unroll
                for (int j = 0; j < 8; j++) split16(vreg[e][j], ph.us[j], pl.us[j]);
                u16* dh = (e < 2) ? Ah : Bh;
                u16* dl = (e < 2) ? Al : Bl;
                int row = (e < 2) ? (srow + e * 64) : srow;
                *(uint4*)(dh + row * 32 + scol) = ph.v;
                *(uint4*)(dl + row * 32 + scol) = pl.v;
            }
            __syncthreads();

            half8 fah[2], fal[2], fbh[4], fbl[4];
#pragma unroll
            for (int i = 0; i < 2; i++) {
                int ra = (w * 32 + i * 16 + lm) * 32 + lk;
                fah[i] = *(const half8*)(Ah + ra);
                fal[i] = *(const half8*)(Al + ra);
            }
#pragma unroll
            for (int i = 0; i < 4; i++) {
                int rb = (i * 16 + lm) * 32 + lk;
                fbh[i] = *(const half8*)(Bh + rb);
                fbl[i] = *(const half8*)(Bl + rb);
            }
#pragma unroll
            for (int mi = 0; mi < 2; mi++)
#pragma unroll
                for (int ni = 0; ni < 4; ni++) {
                    acc[mi][ni] = __builtin_amdgcn_mfma_f32_16x16x32_f16(
                        fal[mi], fbh[ni], acc[mi][ni], 0, 0, 0);
                    acc[mi][ni] = __builtin_amdgcn_mfma_f32_16x16x32_f16(
                        fah[mi], fbl[ni], acc[mi][ni], 0, 0, 0);
                    acc[mi][ni] = __builtin_amdgcn_mfma_f32_16x16x32_f16(
                        fah[mi], fbh[ni], acc[mi][ni], 0, 0, 0);
                }
        }
#pragma unroll
        for (int i = 0; i < 2; i++)
#pragma unroll
            for (int j = 0; j < 4; j++)
#pragma unroll
                for (int r = 0; r < 4; r++) dacc[i][j][r] += (double)acc[i][j][r];
    }

    const int rbase = bm * 128 + w * 32 + (lane >> 4) * 4;
    const int cbase = bn * 64 + lm;
#pragma unroll
    for (int mi = 0; mi < 2; mi++)
#pragma unroll
        for (int ni = 0; ni < 4; ni++) {
            int col = cbase + ni * 16;
            int sel = col >> 10, cc = col & 1023;
            double bias = (sel == 0) ? (double)qbias[cc]
                        : ((sel == 2) ? (double)vbias[cc] : 0.0);
            float* dst = (sel == 0) ? qws : ((sel == 1) ? kws : vws);
#pragma unroll
            for (int r = 0; r < 4; r++) {
                int row = rbase + mi * 16 + r;
                dst[(size_t)row * 1024 + cc] = (float)(dacc[mi][ni][r] + bias);
            }
        }
}

// --- K2a: per-32-group quant of q -> int8 (row-major) + f64 scale ------------
__global__ __launch_bounds__(256) void quant_qk(const float* __restrict__ pre,
                                                signed char* __restrict__ qout,
                                                double* __restrict__ sout) {
    size_t g = (size_t)blockIdx.x * 256 + threadIdx.x;   // 131072 groups
    const float* p = pre + g * 32;
    float v[32];
    float amax = 0.f;
#pragma unroll
    for (int i = 0; i < 8; i++) {
        float4 q4 = ((const float4*)p)[i];
        v[i * 4 + 0] = q4.x; v[i * 4 + 1] = q4.y; v[i * 4 + 2] = q4.z; v[i * 4 + 3] = q4.w;
        amax = fmaxf(amax, fmaxf(fmaxf(fabsf(q4.x), fabsf(q4.y)),
                                 fmaxf(fabsf(q4.z), fabsf(q4.w))));
    }
    double s = fmax((double)amax / 127.0, 1e-8);
    sout[g] = s;
    int pk[8];
#pragma unroll
    for (int i = 0; i < 8; i++) {
        int b0 = (int)fmin(fmax(rint((double)v[i * 4 + 0] / s), -128.0), 127.0);
        int b1 = (int)fmin(fmax(rint((double)v[i * 4 + 1] / s), -128.0), 127.0);
        int b2 = (int)fmin(fmax(rint((double)v[i * 4 + 2] / s), -128.0), 127.0);
        int b3 = (int)fmin(fmax(rint((double)v[i * 4 + 3] / s), -128.0), 127.0);
        pk[i] = (b0 & 255) | ((b1 & 255) << 8) | ((b2 & 255) << 16) | ((b3 & 255) << 24);
    }
    int4* d = (int4*)(qout + g * 32);
    d[0] = make_int4(pk[0], pk[1], pk[2], pk[3]);
    d[1] = make_int4(pk[4], pk[5], pk[6], pk[7]);
}

// --- K2b: per-32-group quant of k -> TRANSPOSED j-major layout ---------------
__global__ __launch_bounds__(256) void quant_k(const float* __restrict__ pre,
                                               int* __restrict__ kT,
                                               double* __restrict__ ksT) {
    size_t g = (size_t)blockIdx.x * 256 + threadIdx.x;   // 131072 groups
    const float* p = pre + g * 32;
    float v[32];
    float amax = 0.f;
#pragma unroll
    for (int i = 0; i < 8; i++) {
        float4 q4 = ((const float4*)p)[i];
        v[i * 4 + 0] = q4.x; v[i * 4 + 1] = q4.y; v[i * 4 + 2] = q4.z; v[i * 4 + 3] = q4.w;
        amax = fmaxf(amax, fmaxf(fmaxf(fabsf(q4.x), fabsf(q4.y)),
                                 fmaxf(fabsf(q4.z), fabsf(q4.w))));
    }
    double s = fmax((double)amax / 127.0, 1e-8);
    int pk[8];
#pragma unroll
    for (int i = 0; i < 8; i++) {
        int b0 = (int)fmin(fmax(rint((double)v[i * 4 + 0] / s), -128.0), 127.0);
        int b1 = (int)fmin(fmax(rint((double)v[i * 4 + 1] / s), -128.0), 127.0);
        int b2 = (int)fmin(fmax(rint((double)v[i * 4 + 2] / s), -128.0), 127.0);
        int b3 = (int)fmin(fmax(rint((double)v[i * 4 + 3] / s), -128.0), 127.0);
        pk[i] = (b0 & 255) | ((b1 & 255) << 8) | ((b2 & 255) << 16) | ((b3 & 255) << 24);
    }
    const int m = (int)((g >> 5) & 1023);
    const int b = (int)(g >> 15);
    const int sub = (int)(g & 31);
    const int h = sub >> 1, pp = sub & 1;
    const int bh = b * 16 + h;
    int* dst = kT + ((size_t)bh * 16 + pp * 8) * 1024 + m;
#pragma unroll
    for (int i = 0; i < 8; i++) dst[i * 1024] = pk[i];
    ksT[((size_t)bh * 2 + pp) * 1024 + m] = s;
}

// --- K3a: partial max|v| over 16-row L-chunks (256 blocks) -------------------
__global__ __launch_bounds__(256) void vmax_part(const float* __restrict__ vws,
                                                 float* __restrict__ pmax) {
    const int lc = blockIdx.x, b = blockIdx.y, t = threadIdx.x;
#pragma unroll
    for (int j = 0; j < 4; j++) {
        int cc = t + j * 256;
        float mx = 0.f;
        for (int l = 0; l < 16; l++)
            mx = fmaxf(mx, fabsf(vws[((size_t)(b * 1024 + lc * 16 + l)) * 1024 + cc]));
        pmax[(size_t)(b * 64 + lc) * 1024 + cc] = mx;
    }
}

// --- K3b: reduce 64 partials -> vs[b*1024+cc] = max(amax/127, eps) f64 -------
__global__ __launch_bounds__(256) void vmax_final(const float* __restrict__ pmax,
                                                  double* __restrict__ vs) {
    int id = blockIdx.x * 256 + threadIdx.x;   // 4096
    int b = id >> 10, cc = id & 1023;
    float mx = 0.f;
    for (int p = 0; p < 64; p++)
        mx = fmaxf(mx, pmax[(size_t)(b * 64 + p) * 1024 + cc]);
    vs[id] = fmax((double)mx / 127.0, 1e-8);
}

// --- K3c: fake-quant v in place (f64 decisions, f32 store) -------------------
__global__ __launch_bounds__(256) void vquant(float* __restrict__ vws,
                                              const double* __restrict__ vs) {
    size_t e = ((size_t)blockIdx.x * 256 + threadIdx.x) * 4;
    int b = (int)(e >> 20), cc = (int)(e & 1023);
    float4 v = *(const float4*)(vws + e);
    double s0 = vs[b * 1024 + cc], s1 = vs[b * 1024 + cc + 1];
    double s2 = vs[b * 1024 + cc + 2], s3 = vs[b * 1024 + cc + 3];
    float4 o;
    o.x = (float)(fmin(fmax(rint((double)v.x / s0), -128.0), 127.0) * s0);
    o.y = (float)(fmin(fmax(rint((double)v.y / s1), -128.0), 127.0) * s1);
    o.z = (float)(fmin(fmax(rint((double)v.z / s2), -128.0), 127.0) * s2);
    o.w = (float)(fmin(fmax(rint((double)v.w / s3), -128.0), 127.0) * s3);
    *(float4*)(vws + e) = o;
}

// ---------------------------------------------------------------------------
// K4: attention, one wave per query row, LDS-staged k (conflict-free), fast
// f64 softmax (custom exp, single reciprocal).
// packed[] aliased onto kTs[] (live ranges disjoint; per-wave private
// slices).  LDS 20480 B -> exactly 8 blocks/CU (32 waves, 100% cap).
// One extra __syncthreads() orders last kTs read before first packed write.
// ---------------------------------------------------------------------------
__global__ __launch_bounds__(256) void attn(const signed char* __restrict__ qint,
                                            const int* __restrict__ kT,
                                            const double* __restrict__ qs,
                                            const double* __restrict__ ksT,
                                            const float* __restrict__ vfq,
                                            const float* __restrict__ abias,
                                            u16* __restrict__ ctx) {
    __shared__ int    kTs[16][256];        // 16 KB  (re-used as packed[] below)
    __shared__ double ks0s[256], ks1s[256];//  4 KB
    u32* const packed = (u32*)&kTs[0][0];  // packed[wv*512 + pos]: (n<<16)|m
    const int t = threadIdx.x;
    const int wv = t >> 6, lane = t & 63;
    const int qt = blockIdx.x, h = blockIdx.y, b = blockIdx.z;
    const int row = qt * 4 + wv;
    const size_t qrow = (size_t)(b * 1024 + row);
    const int bh = b * 16 + h;

    const int* qv = (const int*)(qint + qrow * 1024 + h * 64);
    int qd[16];
#pragma unroll
    for (int j = 0; j < 4; j++) {
        int4 tmp = ((const int4*)qv)[j];
        qd[j * 4 + 0] = tmp.x; qd[j * 4 + 1] = tmp.y;
        qd[j * 4 + 2] = tmp.z; qd[j * 4 + 3] = tmp.w;
    }
    const double sq0 = qs[qrow * 32 + 2 * h], sq1 = qs[qrow * 32 + 2 * h + 1];
    const int* kTg = kT + (size_t)bh * 16384;
    const double* ks0g = ksT + (size_t)(bh * 2) * 1024;
    const double* ks1g = ksT + (size_t)(bh * 2 + 1) * 1024;
    const float* ab = abias + (size_t)row * 1024;

    double sd[16];
    for (int c = 0; c < 4; c++) {
        if (c) __syncthreads();
#pragma unroll
        for (int r = 0; r < 4; r++) {
            const int j = wv * 4 + r;
            int4 val = *(const int4*)(kTg + (size_t)j * 1024 + c * 256 + 4 * lane);
            *(int4*)(&kTs[j][4 * lane]) = val;
        }
        ks0s[t] = ks0g[c * 256 + t];
        ks1s[t] = ks1g[c * 256 + t];
        __syncthreads();
#pragma unroll
        for (int s = 0; s < 4; s++) {
            const int ml = s * 64 + lane;
            int I0 = 0, I1 = 0;
#pragma unroll
            for (int j = 0; j < 8; j++)  I0 = dot4(qd[j], kTs[j][ml], I0);
#pragma unroll
            for (int j = 8; j < 16; j++) I1 = dot4(qd[j], kTs[j][ml], I1);
            sd[c * 4 + s] = 0.125 * (sq0 * ks0s[ml] * (double)I0
                                   + sq1 * ks1s[ml] * (double)I1)
                          + (double)ab[c * 256 + ml];
        }
    }

    // softmax (f64): custom exp, single reciprocal
    double mx = sd[0];
#pragma unroll
    for (int it = 1; it < 16; it++) mx = fmax(mx, sd[it]);
#pragma unroll
    for (int off = 1; off < 64; off <<= 1) mx = fmax(mx, __shfl_xor(mx, off));
    double sum = 0.0;
#pragma unroll
    for (int it = 0; it < 16; it++) {
        double e = fexp(sd[it] - mx);
        sd[it] = e;
        sum += e;
    }
#pragma unroll
    for (int off = 1; off < 64; off <<= 1) sum += __shfl_xor(sum, off);
    const double inv = 1.0 / sum;

    // all waves done reading kTs before we overwrite it with packed[]
    __syncthreads();

    // static quant + ballot compaction of nonzeros (ascending m)
    int base = 0;
#pragma unroll
    for (int it = 0; it < 16; it++) {
        double a = sd[it] * inv;
        double nd = fmin(fmax(rint(a * 255.0), 0.0), 255.0);
        int ni = (int)nd;
        unsigned long long mk = __ballot(ni != 0);
        if (ni != 0) {
            int pos = base + (int)__popcll(mk & ((1ull << lane) - 1ull));
            packed[wv * 512 + pos] = ((u32)ni << 16) | (u32)(it * 64 + lane);
        }
        base += (int)__popcll(mk);
    }
    __syncthreads();

    // AV: lane = head dim; iterate compacted list (wave-uniform trip count)
    float acc = 0.f;
    const float* vcol = vfq + ((size_t)b * 1024) * 1024 + h * 64 + lane;
    for (int j = 0; j < base; ++j) {
        u32 p = packed[wv * 512 + j];
        float a = (float)(p >> 16) / 255.0f;
        acc = fmaf(a, vcol[(size_t)(p & 1023u) * 1024], acc);
    }
    ctx[qrow * 1024 + h * 64 + lane] = f2b(acc);
}

// --- K5: out = ctx @ w_proj^T + b_proj, bf16 MFMA (post-cliff) ---------------
__global__ __launch_bounds__(256) void gemm_proj(const u16* __restrict__ ctx,
                                                 const u16* __restrict__ wproj,
                                                 const float* __restrict__ bproj,
                                                 float* __restrict__ out) {
    typedef __attribute__((ext_vector_type(8))) short short8;
    __shared__ u16 As[128 * 32], Bs[128 * 32];
    f32x4 acc[4][4];
#pragma unroll
    for (int i = 0; i < 4; i++)
#pragma unroll
        for (int j = 0; j < 4; j++) acc[i][j] = (f32x4){0.f, 0.f, 0.f, 0.f};

    const int t = threadIdx.x;
    const int lane = t & 63, w = t >> 6;
    const int wm = w >> 1, wn = w & 1;
    const int srow = t >> 2, scol = (t & 3) * 8;
    const int lm = lane & 15, lk = (lane >> 4) * 8;
    const int bm = blockIdx.y, bn = blockIdx.x;
    const u16* ap = ctx + (size_t)(bm * 128 + srow) * 1024 + scol;
    const u16* bp = wproj + (size_t)(bn * 128 + srow) * 1024 + scol;

    for (int k0 = 0; k0 < 1024; k0 += 32) {
        uint4 a0 = *(const uint4*)(ap + k0);
        uint4 a1 = *(const uint4*)(ap + (size_t)64 * 1024 + k0);
        uint4 b0 = *(const uint4*)(bp + k0);
        uint4 b1 = *(const uint4*)(bp + (size_t)64 * 1024 + k0);
        __syncthreads();
        *(uint4*)(As + srow * 32 + scol) = a0;
        *(uint4*)(As + (srow + 64) * 32 + scol) = a1;
        *(uint4*)(Bs + srow * 32 + scol) = b0;
        *(uint4*)(Bs + (srow + 64) * 32 + scol) = b1;
        __syncthreads();
        short8 af[4], bfr[4];
#pragma unroll
        for (int i = 0; i < 4; i++) {
            af[i]  = *(const short8*)(As + (wm * 64 + i * 16 + lm) * 32 + lk);
            bfr[i] = *(const short8*)(Bs + (wn * 64 + i * 16 + lm) * 32 + lk);
        }
#pragma unroll
        for (int mi = 0; mi < 4; mi++)
#pragma unroll
            for (int ni = 0; ni < 4; ni++)
                acc[mi][ni] = __builtin_amdgcn_mfma_f32_16x16x32_bf16(
                    af[mi], bfr[ni], acc[mi][ni], 0, 0, 0);
    }

    const int rbase = bm * 128 + wm * 64 + (lane >> 4) * 4;
    const int cbase = bn * 128 + wn * 64 + lm;
#pragma unroll
    for (int mi = 0; mi < 4; mi++)
#pragma unroll
        for (int ni = 0; ni < 4; ni++) {
            int col = cbase + ni * 16;
            float bias = bproj[col];
#pragma unroll
            for (int r = 0; r < 4; r++) {
                int row = rbase + mi * 16 + r;
                out[(size_t)row * 1024 + col] = acc[mi][ni][r] + bias;
            }
        }
}

// ---------------------------------------------------------------------------
extern "C" void kernel_launch(void* const* d_in, const int* in_sizes, int n_in,
                              void* d_out, int out_size, void* d_ws, size_t ws_size,
                              hipStream_t stream) {
    const float* x     = (const float*)d_in[0];
    const float* abias = (const float*)d_in[1];
    const float* wqkv  = (const float*)d_in[2];
    const float* qbias = (const float*)d_in[3];
    const float* vbias = (const float*)d_in[4];
    const float* wproj = (const float*)d_in[5];
    const float* bproj = (const float*)d_in[6];
    float* out = (float*)d_out;

    char* ws = (char*)d_ws;
    float*       qpre    = (float*)(ws + 0);
    float*       kpre    = (float*)(ws + 16777216);
    float*       vfq     = (float*)(ws + 33554432);
    u16*         wprojbf = (u16*)  (ws + 50331648);
    signed char* qint    = (signed char*)(ws + 52428800);
    int*         kT      = (int*)  (ws + 56623104);
    double*      qs      = (double*)(ws + 60817408);
    double*      ksT     = (double*)(ws + 61865984);
    double*      vs      = (double*)(ws + 62914560);
    float*       pmax    = (float*)(ws + 62947328);   // 1MB (262144 f32)
    u16*         ctx     = (u16*)(ws + 0);            // alias qpre

    cvt_bf16w<<<1024, 256, 0, stream>>>(wprojbf, wproj, 1048576);
    gemm_qkv3<<<dim3(48, 32), 256, 0, stream>>>(x, wqkv, qbias, vbias,
                                                qpre, kpre, vfq);
    quant_qk<<<512, 256, 0, stream>>>(qpre, qint, qs);
    quant_k<<<512, 256, 0, stream>>>(kpre, kT, ksT);
    vmax_part<<<dim3(64, 4), 256, 0, stream>>>(vfq, pmax);
    vmax_final<<<16, 256, 0, stream>>>(pmax, vs);
    vquant<<<4096, 256, 0, stream>>>(vfq, vs);
    attn<<<dim3(256, 16, 4), 256, 0, stream>>>(qint, kT, qs, ksT, vfq, abias, ctx);
    gemm_proj<<<dim3(8, 32), 256, 0, stream>>>(ctx, wprojbf, bproj, out);
}

// Round 9
// 506.995 us; speedup vs baseline: 4.4617x; 1.0218x over previous
//
#include <hip/hip_runtime.h>

// ---------------------------------------------------------------------------
// QuantSelfAttention on MI355X (gfx950).  B=4, L=1024, C=1024, H=16, D=64.
// Inputs f32, output f32.  Numerics (validated rounds 4-18, absmax 1.89e-3):
//   - qkv GEMM: fp16x2-split 3-pass MFMA + per-128-K-slab f64 accumulation
//   - q/k as int8 + per-32-group f64 scale; scores = exact int dots, f64 rescale
//   - softmax + round(a*255) in f64;  AV + proj GEMM post-cliff (f32/bf16)
// Round 19 (r18 = r11 revert confirmed 518us; attn 283us, VALUBusy 73%):
//   - AV loop only: (a) kill the hidden IEEE f32 divide -- `/255.0f` without
//     fast-math emits div_scale/rcp/fma/div_fixup ~10 ops/iter; replaced by
//     compile-time `*(1.0f/255.0f)` (<=1 ulp; AV summation order/rounding
//     proven benign by r12-r14: exact-int AV gave bit-identical absmax).
//     (b) 4-wide unroll: one wave-uniform uint4 LDS read per 4 entries,
//     4 independent accumulators (breaks serial fmaf chain, overlaps the
//     4 coalesced vcol loads), scalar remainder.
//   - everything else byte-identical to the 518us kernel.
//
// ws byte layout:
//   0         qpre   16MB f32   [aliased as ctx (bf16 8MB) after quant]
//   16777216  kpre   16MB f32
//   33554432  vfq    16MB f32
//   50331648  wprojbf 2MB u16
//   52428800  qint   4MB int8
//   56623104  kT     4MB int32 (64 bh x 16 j x 1024 m)
//   60817408  qs     1MB f64 (131072 groups)
//   61865984  ksT    1MB f64 (64 bh x 2 p x 1024 m)
//   62914560  vs     32KB f64 (4096)
//   62947328  pmax   1MB f32 (262144)   -> high-water 64.0MB (<67.3MB proven)
// ---------------------------------------------------------------------------

typedef unsigned short u16;
typedef unsigned int u32;
typedef __attribute__((ext_vector_type(8))) _Float16 half8;  // 8 f16 (4 VGPRs)
typedef __attribute__((ext_vector_type(4))) float f32x4;     // MFMA accumulator

__device__ __forceinline__ u16 f2b(float f) {   // f32 -> bf16 RNE
    u32 i;
    __builtin_memcpy(&i, &f, 4);
    return (u16)((i + 0x7FFFu + ((i >> 16) & 1u)) >> 16);
}

__device__ __forceinline__ void split16(float v, u16& hi, u16& lo) {
    _Float16 h = (_Float16)v;
    _Float16 l = (_Float16)(v - (float)h);
    __builtin_memcpy(&hi, &h, 2);
    __builtin_memcpy(&lo, &l, 2);
}

__device__ __forceinline__ int dot4(int a, int b, int c) {
#if __has_builtin(__builtin_amdgcn_sdot4)
    return __builtin_amdgcn_sdot4(a, b, c, false);
#else
    int r = c;
    r += ((a << 24) >> 24) * ((b << 24) >> 24);
    r += ((a << 16) >> 24) * ((b << 16) >> 24);
    r += ((a << 8) >> 24) * ((b << 8) >> 24);
    r += (a >> 24) * (b >> 24);
    return r;
#endif
}

// fast f64 exp for x <= 0 (scores are max-subtracted).  Cody-Waite range
// reduction + degree-10 Taylor (rel err ~2e-13) + exponent bit-add.
// exp(0) == 1.0 exactly.  x < -700 -> 0 (true value < 1e-304; a rounds to 0).
__device__ __forceinline__ double fexp(double x) {
    double kd = rint(x * 1.4426950408889634);
    double r = fma(kd, -6.93147180369123816490e-01, x);
    r = fma(kd, -1.90821492927058770002e-10, r);
    double p = 2.7557319223985888e-07;
    p = fma(p, r, 2.7557319223985890e-06);
    p = fma(p, r, 2.4801587301587302e-05);
    p = fma(p, r, 1.9841269841269841e-04);
    p = fma(p, r, 1.3888888888888889e-03);
    p = fma(p, r, 8.3333333333333333e-03);
    p = fma(p, r, 4.1666666666666664e-02);
    p = fma(p, r, 1.6666666666666666e-01);
    p = fma(p, r, 0.5);
    p = fma(p, r, 1.0);
    p = fma(p, r, 1.0);
    long long bits;
    __builtin_memcpy(&bits, &p, 8);
    bits += ((long long)kd) << 52;
    double e;
    __builtin_memcpy(&e, &bits, 8);
    return (x < -700.0) ? 0.0 : e;
}

// --- K0: w_proj f32 -> bf16 --------------------------------------------------
__global__ __launch_bounds__(256) void cvt_bf16w(u16* __restrict__ dst,
                                                 const float* __restrict__ src, int n) {
    int i = (blockIdx.x * 256 + threadIdx.x) * 4;
    if (i + 3 < n) {
        float4 v = *(const float4*)(src + i);
        ushort4 o;
        o.x = f2b(v.x); o.y = f2b(v.y); o.z = f2b(v.z); o.w = f2b(v.w);
        *(ushort4*)(dst + i) = o;
    }
}

// ---------------------------------------------------------------------------
// K1: qkv = x @ w_qkv^T + bias, fp16x2-split 3-pass MFMA, f64 slab accumulate.
// 128x64 output blocks (grid 48 x 32).  Per-output K-order identical to the
// round-4..18 passing versions -> bit-identical results.
// ---------------------------------------------------------------------------
__global__ __launch_bounds__(256) void gemm_qkv3(const float* __restrict__ A,
                                                 const float* __restrict__ Bm,
                                                 const float* __restrict__ qbias,
                                                 const float* __restrict__ vbias,
                                                 float* __restrict__ qws,
                                                 float* __restrict__ kws,
                                                 float* __restrict__ vws) {
    __shared__ u16 Ah[128 * 32], Al[128 * 32], Bh[64 * 32], Bl[64 * 32];
    const int t = threadIdx.x;
    const int lane = t & 63, w = t >> 6;
    const int srow = t >> 2, scol = (t & 3) * 8;
    const int lm = lane & 15, lk = (lane >> 4) * 8;
    const int bm = blockIdx.y, bn = blockIdx.x;

    const float* ap = A + (size_t)(bm * 128 + srow) * 1024 + scol;
    const float* bp = Bm + (size_t)(bn * 64 + srow) * 1024 + scol;

    double dacc[2][4][4];
#pragma unroll
    for (int i = 0; i < 2; i++)
#pragma unroll
        for (int j = 0; j < 4; j++)
#pragma unroll
            for (int r = 0; r < 4; r++) dacc[i][j][r] = 0.0;

    for (int slab = 0; slab < 8; slab++) {
        f32x4 acc[2][4];
#pragma unroll
        for (int i = 0; i < 2; i++)
#pragma unroll
            for (int j = 0; j < 4; j++) acc[i][j] = (f32x4){0.f, 0.f, 0.f, 0.f};

        for (int kc = 0; kc < 4; kc++) {
            const int k0 = slab * 128 + kc * 32;
            float vreg[3][8];
#pragma unroll
            for (int e = 0; e < 3; e++) {
                const float* src = (e < 2) ? (ap + e * (size_t)64 * 1024 + k0)
                                           : (bp + k0);
                float4 v0 = *(const float4*)(src);
                float4 v1 = *(const float4*)(src + 4);
                vreg[e][0] = v0.x; vreg[e][1] = v0.y; vreg[e][2] = v0.z; vreg[e][3] = v0.w;
                vreg[e][4] = v1.x; vreg[e][5] = v1.y; vreg[e][6] = v1.z; vreg[e][7] = v1.w;
            }
            __syncthreads();
#pragma unroll
            for (int e = 0; e < 3; e++) {
                union { u16 us[8]; uint4 v; } ph, pl;
#pragma unroll
                for (int j = 0; j < 8; j++) split16(vreg[e][j], ph.us[j], pl.us[j]);
                u16* dh = (e < 2) ? Ah : Bh;
                u16* dl = (e < 2) ? Al : Bl;
                int row = (e < 2) ? (srow + e * 64) : srow;
                *(uint4*)(dh + row * 32 + scol) = ph.v;
                *(uint4*)(dl + row * 32 + scol) = pl.v;
            }
            __syncthreads();

            half8 fah[2], fal[2], fbh[4], fbl[4];
#pragma unroll
            for (int i = 0; i < 2; i++) {
                int ra = (w * 32 + i * 16 + lm) * 32 + lk;
                fah[i] = *(const half8*)(Ah + ra);
                fal[i] = *(const half8*)(Al + ra);
            }
#pragma unroll
            for (int i = 0; i < 4; i++) {
                int rb = (i * 16 + lm) * 32 + lk;
                fbh[i] = *(const half8*)(Bh + rb);
                fbl[i] = *(const half8*)(Bl + rb);
            }
#pragma unroll
            for (int mi = 0; mi < 2; mi++)
#pragma unroll
                for (int ni = 0; ni < 4; ni++) {
                    acc[mi][ni] = __builtin_amdgcn_mfma_f32_16x16x32_f16(
                        fal[mi], fbh[ni], acc[mi][ni], 0, 0, 0);
                    acc[mi][ni] = __builtin_amdgcn_mfma_f32_16x16x32_f16(
                        fah[mi], fbl[ni], acc[mi][ni], 0, 0, 0);
                    acc[mi][ni] = __builtin_amdgcn_mfma_f32_16x16x32_f16(
                        fah[mi], fbh[ni], acc[mi][ni], 0, 0, 0);
                }
        }
#pragma unroll
        for (int i = 0; i < 2; i++)
#pragma unroll
            for (int j = 0; j < 4; j++)
#pragma unroll
                for (int r = 0; r < 4; r++) dacc[i][j][r] += (double)acc[i][j][r];
    }

    const int rbase = bm * 128 + w * 32 + (lane >> 4) * 4;
    const int cbase = bn * 64 + lm;
#pragma unroll
    for (int mi = 0; mi < 2; mi++)
#pragma unroll
        for (int ni = 0; ni < 4; ni++) {
            int col = cbase + ni * 16;
            int sel = col >> 10, cc = col & 1023;
            double bias = (sel == 0) ? (double)qbias[cc]
                        : ((sel == 2) ? (double)vbias[cc] : 0.0);
            float* dst = (sel == 0) ? qws : ((sel == 1) ? kws : vws);
#pragma unroll
            for (int r = 0; r < 4; r++) {
                int row = rbase + mi * 16 + r;
                dst[(size_t)row * 1024 + cc] = (float)(dacc[mi][ni][r] + bias);
            }
        }
}

// --- K2a: per-32-group quant of q -> int8 (row-major) + f64 scale ------------
__global__ __launch_bounds__(256) void quant_qk(const float* __restrict__ pre,
                                                signed char* __restrict__ qout,
                                                double* __restrict__ sout) {
    size_t g = (size_t)blockIdx.x * 256 + threadIdx.x;   // 131072 groups
    const float* p = pre + g * 32;
    float v[32];
    float amax = 0.f;
#pragma unroll
    for (int i = 0; i < 8; i++) {
        float4 q4 = ((const float4*)p)[i];
        v[i * 4 + 0] = q4.x; v[i * 4 + 1] = q4.y; v[i * 4 + 2] = q4.z; v[i * 4 + 3] = q4.w;
        amax = fmaxf(amax, fmaxf(fmaxf(fabsf(q4.x), fabsf(q4.y)),
                                 fmaxf(fabsf(q4.z), fabsf(q4.w))));
    }
    double s = fmax((double)amax / 127.0, 1e-8);
    sout[g] = s;
    int pk[8];
#pragma unroll
    for (int i = 0; i < 8; i++) {
        int b0 = (int)fmin(fmax(rint((double)v[i * 4 + 0] / s), -128.0), 127.0);
        int b1 = (int)fmin(fmax(rint((double)v[i * 4 + 1] / s), -128.0), 127.0);
        int b2 = (int)fmin(fmax(rint((double)v[i * 4 + 2] / s), -128.0), 127.0);
        int b3 = (int)fmin(fmax(rint((double)v[i * 4 + 3] / s), -128.0), 127.0);
        pk[i] = (b0 & 255) | ((b1 & 255) << 8) | ((b2 & 255) << 16) | ((b3 & 255) << 24);
    }
    int4* d = (int4*)(qout + g * 32);
    d[0] = make_int4(pk[0], pk[1], pk[2], pk[3]);
    d[1] = make_int4(pk[4], pk[5], pk[6], pk[7]);
}

// --- K2b: per-32-group quant of k -> TRANSPOSED j-major layout ---------------
__global__ __launch_bounds__(256) void quant_k(const float* __restrict__ pre,
                                               int* __restrict__ kT,
                                               double* __restrict__ ksT) {
    size_t g = (size_t)blockIdx.x * 256 + threadIdx.x;   // 131072 groups
    const float* p = pre + g * 32;
    float v[32];
    float amax = 0.f;
#pragma unroll
    for (int i = 0; i < 8; i++) {
        float4 q4 = ((const float4*)p)[i];
        v[i * 4 + 0] = q4.x; v[i * 4 + 1] = q4.y; v[i * 4 + 2] = q4.z; v[i * 4 + 3] = q4.w;
        amax = fmaxf(amax, fmaxf(fmaxf(fabsf(q4.x), fabsf(q4.y)),
                                 fmaxf(fabsf(q4.z), fabsf(q4.w))));
    }
    double s = fmax((double)amax / 127.0, 1e-8);
    int pk[8];
#pragma unroll
    for (int i = 0; i < 8; i++) {
        int b0 = (int)fmin(fmax(rint((double)v[i * 4 + 0] / s), -128.0), 127.0);
        int b1 = (int)fmin(fmax(rint((double)v[i * 4 + 1] / s), -128.0), 127.0);
        int b2 = (int)fmin(fmax(rint((double)v[i * 4 + 2] / s), -128.0), 127.0);
        int b3 = (int)fmin(fmax(rint((double)v[i * 4 + 3] / s), -128.0), 127.0);
        pk[i] = (b0 & 255) | ((b1 & 255) << 8) | ((b2 & 255) << 16) | ((b3 & 255) << 24);
    }
    const int m = (int)((g >> 5) & 1023);
    const int b = (int)(g >> 15);
    const int sub = (int)(g & 31);
    const int h = sub >> 1, pp = sub & 1;
    const int bh = b * 16 + h;
    int* dst = kT + ((size_t)bh * 16 + pp * 8) * 1024 + m;
#pragma unroll
    for (int i = 0; i < 8; i++) dst[i * 1024] = pk[i];
    ksT[((size_t)bh * 2 + pp) * 1024 + m] = s;
}

// --- K3a: partial max|v| over 16-row L-chunks (256 blocks) -------------------
__global__ __launch_bounds__(256) void vmax_part(const float* __restrict__ vws,
                                                 float* __restrict__ pmax) {
    const int lc = blockIdx.x, b = blockIdx.y, t = threadIdx.x;
#pragma unroll
    for (int j = 0; j < 4; j++) {
        int cc = t + j * 256;
        float mx = 0.f;
        for (int l = 0; l < 16; l++)
            mx = fmaxf(mx, fabsf(vws[((size_t)(b * 1024 + lc * 16 + l)) * 1024 + cc]));
        pmax[(size_t)(b * 64 + lc) * 1024 + cc] = mx;
    }
}

// --- K3b: reduce 64 partials -> vs[b*1024+cc] = max(amax/127, eps) f64 -------
__global__ __launch_bounds__(256) void vmax_final(const float* __restrict__ pmax,
                                                  double* __restrict__ vs) {
    int id = blockIdx.x * 256 + threadIdx.x;   // 4096
    int b = id >> 10, cc = id & 1023;
    float mx = 0.f;
    for (int p = 0; p < 64; p++)
        mx = fmaxf(mx, pmax[(size_t)(b * 64 + p) * 1024 + cc]);
    vs[id] = fmax((double)mx / 127.0, 1e-8);
}

// --- K3c: fake-quant v in place (f64 decisions, f32 store) -------------------
__global__ __launch_bounds__(256) void vquant(float* __restrict__ vws,
                                              const double* __restrict__ vs) {
    size_t e = ((size_t)blockIdx.x * 256 + threadIdx.x) * 4;
    int b = (int)(e >> 20), cc = (int)(e & 1023);
    float4 v = *(const float4*)(vws + e);
    double s0 = vs[b * 1024 + cc], s1 = vs[b * 1024 + cc + 1];
    double s2 = vs[b * 1024 + cc + 2], s3 = vs[b * 1024 + cc + 3];
    float4 o;
    o.x = (float)(fmin(fmax(rint((double)v.x / s0), -128.0), 127.0) * s0);
    o.y = (float)(fmin(fmax(rint((double)v.y / s1), -128.0), 127.0) * s1);
    o.z = (float)(fmin(fmax(rint((double)v.z / s2), -128.0), 127.0) * s2);
    o.w = (float)(fmin(fmax(rint((double)v.w / s3), -128.0), 127.0) * s3);
    *(float4*)(vws + e) = o;
}

// ---------------------------------------------------------------------------
// K4: attention, one wave per query row, LDS-staged k (conflict-free), fast
// f64 softmax (custom exp, single reciprocal).
// packed[] aliased onto kTs[] (live ranges disjoint; per-wave private
// slices).  LDS 20480 B -> exactly 8 blocks/CU (32 waves, 100% cap).
// Round 19: AV loop -- divide killed (*1/255 const), 4-wide uint4 LDS
// reads, 4 independent accumulators (order change proven benign r12-r14).
// ---------------------------------------------------------------------------
__global__ __launch_bounds__(256) void attn(const signed char* __restrict__ qint,
                                            const int* __restrict__ kT,
                                            const double* __restrict__ qs,
                                            const double* __restrict__ ksT,
                                            const float* __restrict__ vfq,
                                            const float* __restrict__ abias,
                                            u16* __restrict__ ctx) {
    __shared__ int    kTs[16][256];        // 16 KB  (re-used as packed[] below)
    __shared__ double ks0s[256], ks1s[256];//  4 KB
    u32* const packed = (u32*)&kTs[0][0];  // packed[wv*512 + pos]: (n<<16)|m
    const int t = threadIdx.x;
    const int wv = t >> 6, lane = t & 63;
    const int qt = blockIdx.x, h = blockIdx.y, b = blockIdx.z;
    const int row = qt * 4 + wv;
    const size_t qrow = (size_t)(b * 1024 + row);
    const int bh = b * 16 + h;

    const int* qv = (const int*)(qint + qrow * 1024 + h * 64);
    int qd[16];
#pragma unroll
    for (int j = 0; j < 4; j++) {
        int4 tmp = ((const int4*)qv)[j];
        qd[j * 4 + 0] = tmp.x; qd[j * 4 + 1] = tmp.y;
        qd[j * 4 + 2] = tmp.z; qd[j * 4 + 3] = tmp.w;
    }
    const double sq0 = qs[qrow * 32 + 2 * h], sq1 = qs[qrow * 32 + 2 * h + 1];
    const int* kTg = kT + (size_t)bh * 16384;
    const double* ks0g = ksT + (size_t)(bh * 2) * 1024;
    const double* ks1g = ksT + (size_t)(bh * 2 + 1) * 1024;
    const float* ab = abias + (size_t)row * 1024;

    double sd[16];
    for (int c = 0; c < 4; c++) {
        if (c) __syncthreads();
#pragma unroll
        for (int r = 0; r < 4; r++) {
            const int j = wv * 4 + r;
            int4 val = *(const int4*)(kTg + (size_t)j * 1024 + c * 256 + 4 * lane);
            *(int4*)(&kTs[j][4 * lane]) = val;
        }
        ks0s[t] = ks0g[c * 256 + t];
        ks1s[t] = ks1g[c * 256 + t];
        __syncthreads();
#pragma unroll
        for (int s = 0; s < 4; s++) {
            const int ml = s * 64 + lane;
            int I0 = 0, I1 = 0;
#pragma unroll
            for (int j = 0; j < 8; j++)  I0 = dot4(qd[j], kTs[j][ml], I0);
#pragma unroll
            for (int j = 8; j < 16; j++) I1 = dot4(qd[j], kTs[j][ml], I1);
            sd[c * 4 + s] = 0.125 * (sq0 * ks0s[ml] * (double)I0
                                   + sq1 * ks1s[ml] * (double)I1)
                          + (double)ab[c * 256 + ml];
        }
    }

    // softmax (f64): custom exp, single reciprocal
    double mx = sd[0];
#pragma unroll
    for (int it = 1; it < 16; it++) mx = fmax(mx, sd[it]);
#pragma unroll
    for (int off = 1; off < 64; off <<= 1) mx = fmax(mx, __shfl_xor(mx, off));
    double sum = 0.0;
#pragma unroll
    for (int it = 0; it < 16; it++) {
        double e = fexp(sd[it] - mx);
        sd[it] = e;
        sum += e;
    }
#pragma unroll
    for (int off = 1; off < 64; off <<= 1) sum += __shfl_xor(sum, off);
    const double inv = 1.0 / sum;

    // all waves done reading kTs before we overwrite it with packed[]
    __syncthreads();

    // static quant + ballot compaction of nonzeros (ascending m)
    int base = 0;
#pragma unroll
    for (int it = 0; it < 16; it++) {
        double a = sd[it] * inv;
        double nd = fmin(fmax(rint(a * 255.0), 0.0), 255.0);
        int ni = (int)nd;
        unsigned long long mk = __ballot(ni != 0);
        if (ni != 0) {
            int pos = base + (int)__popcll(mk & ((1ull << lane) - 1ull));
            packed[wv * 512 + pos] = ((u32)ni << 16) | (u32)(it * 64 + lane);
        }
        base += (int)__popcll(mk);
    }
    __syncthreads();

    // AV: lane = head dim; iterate compacted list (wave-uniform trip count).
    // r19: no divide (mul by 1/255 const), 4-wide uint4 LDS reads, 4
    // independent accumulators.  Order change proven benign (r12-r14).
    const float r255 = 1.0f / 255.0f;   // compile-time constant
    float acc0 = 0.f, acc1 = 0.f, acc2 = 0.f, acc3 = 0.f;
    const float* vcol = vfq + ((size_t)b * 1024) * 1024 + h * 64 + lane;
    const u32* pk = packed + wv * 512;
    int j = 0;
    for (; j + 4 <= base; j += 4) {
        uint4 p4 = *(const uint4*)(pk + j);
        float v0 = vcol[(size_t)(p4.x & 1023u) * 1024];
        float v1 = vcol[(size_t)(p4.y & 1023u) * 1024];
        float v2 = vcol[(size_t)(p4.z & 1023u) * 1024];
        float v3 = vcol[(size_t)(p4.w & 1023u) * 1024];
        acc0 = fmaf((float)(p4.x >> 16) * r255, v0, acc0);
        acc1 = fmaf((float)(p4.y >> 16) * r255, v1, acc1);
        acc2 = fmaf((float)(p4.z >> 16) * r255, v2, acc2);
        acc3 = fmaf((float)(p4.w >> 16) * r255, v3, acc3);
    }
    for (; j < base; ++j) {
        u32 p = pk[j];
        acc0 = fmaf((float)(p >> 16) * r255, vcol[(size_t)(p & 1023u) * 1024], acc0);
    }
    float acc = (acc0 + acc1) + (acc2 + acc3);
    ctx[qrow * 1024 + h * 64 + lane] = f2b(acc);
}

// --- K5: out = ctx @ w_proj^T + b_proj, bf16 MFMA (post-cliff) ---------------
__global__ __launch_bounds__(256) void gemm_proj(const u16* __restrict__ ctx,
                                                 const u16* __restrict__ wproj,
                                                 const float* __restrict__ bproj,
                                                 float* __restrict__ out) {
    typedef __attribute__((ext_vector_type(8))) short short8;
    __shared__ u16 As[128 * 32], Bs[128 * 32];
    f32x4 acc[4][4];
#pragma unroll
    for (int i = 0; i < 4; i++)
#pragma unroll
        for (int j = 0; j < 4; j++) acc[i][j] = (f32x4){0.f, 0.f, 0.f, 0.f};

    const int t = threadIdx.x;
    const int lane = t & 63, w = t >> 6;
    const int wm = w >> 1, wn = w & 1;
    const int srow = t >> 2, scol = (t & 3) * 8;
    const int lm = lane & 15, lk = (lane >> 4) * 8;
    const int bm = blockIdx.y, bn = blockIdx.x;
    const u16* ap = ctx + (size_t)(bm * 128 + srow) * 1024 + scol;
    const u16* bp = wproj + (size_t)(bn * 128 + srow) * 1024 + scol;

    for (int k0 = 0; k0 < 1024; k0 += 32) {
        uint4 a0 = *(const uint4*)(ap + k0);
        uint4 a1 = *(const uint4*)(ap + (size_t)64 * 1024 + k0);
        uint4 b0 = *(const uint4*)(bp + k0);
        uint4 b1 = *(const uint4*)(bp + (size_t)64 * 1024 + k0);
        __syncthreads();
        *(uint4*)(As + srow * 32 + scol) = a0;
        *(uint4*)(As + (srow + 64) * 32 + scol) = a1;
        *(uint4*)(Bs + srow * 32 + scol) = b0;
        *(uint4*)(Bs + (srow + 64) * 32 + scol) = b1;
        __syncthreads();
        short8 af[4], bfr[4];
#pragma unroll
        for (int i = 0; i < 4; i++) {
            af[i]  = *(const short8*)(As + (wm * 64 + i * 16 + lm) * 32 + lk);
            bfr[i] = *(const short8*)(Bs + (wn * 64 + i * 16 + lm) * 32 + lk);
        }
#pragma unroll
        for (int mi = 0; mi < 4; mi++)
#pragma unroll
            for (int ni = 0; ni < 4; ni++)
                acc[mi][ni] = __builtin_amdgcn_mfma_f32_16x16x32_bf16(
                    af[mi], bfr[ni], acc[mi][ni], 0, 0, 0);
    }

    const int rbase = bm * 128 + wm * 64 + (lane >> 4) * 4;
    const int cbase = bn * 128 + wn * 64 + lm;
#pragma unroll
    for (int mi = 0; mi < 4; mi++)
#pragma unroll
        for (int ni = 0; ni < 4; ni++) {
            int col = cbase + ni * 16;
            float bias = bproj[col];
#pragma unroll
            for (int r = 0; r < 4; r++) {
                int row = rbase + mi * 16 + r;
                out[(size_t)row * 1024 + col] = acc[mi][ni][r] + bias;
            }
        }
}

// ---------------------------------------------------------------------------
extern "C" void kernel_launch(void* const* d_in, const int* in_sizes, int n_in,
                              void* d_out, int out_size, void* d_ws, size_t ws_size,
                              hipStream_t stream) {
    const float* x     = (const float*)d_in[0];
    const float* abias = (const float*)d_in[1];
    const float* wqkv  = (const float*)d_in[2];
    const float* qbias = (const float*)d_in[3];
    const float* vbias = (const float*)d_in[4];
    const float* wproj = (const float*)d_in[5];
    const float* bproj = (const float*)d_in[6];
    float* out = (float*)d_out;

    char* ws = (char*)d_ws;
    float*       qpre    = (float*)(ws + 0);
    float*       kpre    = (float*)(ws + 16777216);
    float*       vfq     = (float*)(ws + 33554432);
    u16*         wprojbf = (u16*)  (ws + 50331648);
    signed char* qint    = (signed char*)(ws + 52428800);
    int*         kT      = (int*)  (ws + 56623104);
    double*      qs      = (double*)(ws + 60817408);
    double*      ksT     = (double*)(ws + 61865984);
    double*      vs      = (double*)(ws + 62914560);
    float*       pmax    = (float*)(ws + 62947328);   // 1MB (262144 f32)
    u16*         ctx     = (u16*)(ws + 0);            // alias qpre

    cvt_bf16w<<<1024, 256, 0, stream>>>(wprojbf, wproj, 1048576);
    gemm_qkv3<<<dim3(48, 32), 256, 0, stream>>>(x, wqkv, qbias, vbias,
                                                qpre, kpre, vfq);
    quant_qk<<<512, 256, 0, stream>>>(qpre, qint, qs);
    quant_k<<<512, 256, 0, stream>>>(kpre, kT, ksT);
    vmax_part<<<dim3(64, 4), 256, 0, stream>>>(vfq, pmax);
    vmax_final<<<16, 256, 0, stream>>>(pmax, vs);
    vquant<<<4096, 256, 0, stream>>>(vfq, vs);
    attn<<<dim3(256, 16, 4), 256, 0, stream>>>(qint, kT, qs, ksT, vfq, abias, ctx);
    gemm_proj<<<dim3(8, 32), 256, 0, stream>>>(ctx, wprojbf, bproj, out);
}

// Round 10
// 472.657 us; speedup vs baseline: 4.7858x; 1.0726x over previous
//
#include <hip/hip_runtime.h>

// ---------------------------------------------------------------------------
// QuantSelfAttention on MI355X (gfx950).  B=4, L=1024, C=1024, H=16, D=64.
// Inputs f32, output f32.  Numerics (validated rounds 4-19, absmax 1.89e-3):
//   - qkv GEMM: fp16x2-split 3-pass MFMA + per-128-K-slab f64 accumulation
//   - q/k as int8 + per-32-group f64 scale; scores = exact int dots, f64 rescale
//   - softmax + round(a*255) in f64;  AV + proj GEMM post-cliff (f32/bf16)
// Round 20 (r19 banked 507us: attn 257us VALUBusy 62%, leave untouched;
// gemm_qkv3 ~165us @ MfmaUtil 19% VALUBusy 30% is next -- split16 re-done
// per block, A-share redundant 48x):
//   - presplit x -> xh/xl (f16 hi/lo) ONCE into the 48-64MB region (dead
//     during gemm; cvt_bf16w moved after gemm).  gemm_qkv3n (r14-proven,
//     bit-identical) stages A via pure uint4 copies; w split in-kernel.
//   - attn/quant/vmax/vquant/gemm_proj byte-identical to r19.
//
// ws byte layout:
//   0         qpre   16MB f32   [aliased as ctx (bf16 8MB) after quant]
//   16777216  kpre   16MB f32
//   33554432  vfq    16MB f32
//   50331648  wprojbf 2MB u16   [xh 8MB @48M during presplit+gemm]
//   52428800  qint   4MB int8
//   56623104  kT     4MB int32  [xl 8MB @56M during presplit+gemm]
//   60817408  qs     1MB f64
//   61865984  ksT    1MB f64
//   62914560  vs     32KB f64
//   62947328  pmax   1MB f32    -> high-water 64.0MB (<67.3MB proven)
// ---------------------------------------------------------------------------

typedef unsigned short u16;
typedef unsigned int u32;
typedef __attribute__((ext_vector_type(8))) _Float16 half8;  // 8 f16 (4 VGPRs)
typedef __attribute__((ext_vector_type(4))) float f32x4;     // MFMA accumulator

__device__ __forceinline__ u16 f2b(float f) {   // f32 -> bf16 RNE
    u32 i;
    __builtin_memcpy(&i, &f, 4);
    return (u16)((i + 0x7FFFu + ((i >> 16) & 1u)) >> 16);
}

__device__ __forceinline__ void split16(float v, u16& hi, u16& lo) {
    _Float16 h = (_Float16)v;
    _Float16 l = (_Float16)(v - (float)h);
    __builtin_memcpy(&hi, &h, 2);
    __builtin_memcpy(&lo, &l, 2);
}

__device__ __forceinline__ int dot4(int a, int b, int c) {
#if __has_builtin(__builtin_amdgcn_sdot4)
    return __builtin_amdgcn_sdot4(a, b, c, false);
#else
    int r = c;
    r += ((a << 24) >> 24) * ((b << 24) >> 24);
    r += ((a << 16) >> 24) * ((b << 16) >> 24);
    r += ((a << 8) >> 24) * ((b << 8) >> 24);
    r += (a >> 24) * (b >> 24);
    return r;
#endif
}

// fast f64 exp for x <= 0 (scores are max-subtracted).  Cody-Waite range
// reduction + degree-10 Taylor (rel err ~2e-13) + exponent bit-add.
// exp(0) == 1.0 exactly.  x < -700 -> 0 (true value < 1e-304; a rounds to 0).
__device__ __forceinline__ double fexp(double x) {
    double kd = rint(x * 1.4426950408889634);
    double r = fma(kd, -6.93147180369123816490e-01, x);
    r = fma(kd, -1.90821492927058770002e-10, r);
    double p = 2.7557319223985888e-07;
    p = fma(p, r, 2.7557319223985890e-06);
    p = fma(p, r, 2.4801587301587302e-05);
    p = fma(p, r, 1.9841269841269841e-04);
    p = fma(p, r, 1.3888888888888889e-03);
    p = fma(p, r, 8.3333333333333333e-03);
    p = fma(p, r, 4.1666666666666664e-02);
    p = fma(p, r, 1.6666666666666666e-01);
    p = fma(p, r, 0.5);
    p = fma(p, r, 1.0);
    p = fma(p, r, 1.0);
    long long bits;
    __builtin_memcpy(&bits, &p, 8);
    bits += ((long long)kd) << 52;
    double e;
    __builtin_memcpy(&e, &bits, 8);
    return (x < -700.0) ? 0.0 : e;
}

// --- K-1: presplit x -> f16 hi/lo (once; removes per-block A re-splits) ------
__global__ __launch_bounds__(256) void presplit(const float* __restrict__ src,
                                                u16* __restrict__ dh,
                                                u16* __restrict__ dl, int n) {
    int i = (blockIdx.x * 256 + threadIdx.x) * 4;
    if (i + 3 < n) {
        float4 v = *(const float4*)(src + i);
        ushort4 h, l;
        split16(v.x, h.x, l.x);
        split16(v.y, h.y, l.y);
        split16(v.z, h.z, l.z);
        split16(v.w, h.w, l.w);
        *(ushort4*)(dh + i) = h;
        *(ushort4*)(dl + i) = l;
    }
}

// --- K0: w_proj f32 -> bf16 (runs AFTER gemm: region aliases xh) -------------
__global__ __launch_bounds__(256) void cvt_bf16w(u16* __restrict__ dst,
                                                 const float* __restrict__ src, int n) {
    int i = (blockIdx.x * 256 + threadIdx.x) * 4;
    if (i + 3 < n) {
        float4 v = *(const float4*)(src + i);
        ushort4 o;
        o.x = f2b(v.x); o.y = f2b(v.y); o.z = f2b(v.z); o.w = f2b(v.w);
        *(ushort4*)(dst + i) = o;
    }
}

// ---------------------------------------------------------------------------
// K1: qkv = x @ w_qkv^T + bias.  A (x) pre-split into xh/xl -> staged to LDS
// by pure 16B copies; w split in-kernel (unchanged).  MFMA sequence, slab
// structure, and dacc order identical to rounds 4-19 -> bit-identical
// (proven in r14's passing run).
// ---------------------------------------------------------------------------
__global__ __launch_bounds__(256) void gemm_qkv3n(const u16* __restrict__ Ahg,
                                                  const u16* __restrict__ Alg,
                                                  const float* __restrict__ Bm,
                                                  const float* __restrict__ qbias,
                                                  const float* __restrict__ vbias,
                                                  float* __restrict__ qws,
                                                  float* __restrict__ kws,
                                                  float* __restrict__ vws) {
    __shared__ u16 Ah[128 * 32], Al[128 * 32], Bh[64 * 32], Bl[64 * 32];
    const int t = threadIdx.x;
    const int lane = t & 63, w = t >> 6;
    const int srow = t >> 2, scol = (t & 3) * 8;
    const int lm = lane & 15, lk = (lane >> 4) * 8;
    const int bm = blockIdx.y, bn = blockIdx.x;

    const u16* aph = Ahg + (size_t)(bm * 128 + srow) * 1024 + scol;
    const u16* apl = Alg + (size_t)(bm * 128 + srow) * 1024 + scol;
    const float* bp = Bm + (size_t)(bn * 64 + srow) * 1024 + scol;

    double dacc[2][4][4];
#pragma unroll
    for (int i = 0; i < 2; i++)
#pragma unroll
        for (int j = 0; j < 4; j++)
#pragma unroll
            for (int r = 0; r < 4; r++) dacc[i][j][r] = 0.0;

    for (int slab = 0; slab < 8; slab++) {
        f32x4 acc[2][4];
#pragma unroll
        for (int i = 0; i < 2; i++)
#pragma unroll
            for (int j = 0; j < 4; j++) acc[i][j] = (f32x4){0.f, 0.f, 0.f, 0.f};

        for (int kc = 0; kc < 4; kc++) {
            const int k0 = slab * 128 + kc * 32;
            uint4 a0h = *(const uint4*)(aph + k0);
            uint4 a1h = *(const uint4*)(aph + (size_t)64 * 1024 + k0);
            uint4 a0l = *(const uint4*)(apl + k0);
            uint4 a1l = *(const uint4*)(apl + (size_t)64 * 1024 + k0);
            float wv[8];
            {
                float4 v0 = *(const float4*)(bp + k0);
                float4 v1 = *(const float4*)(bp + k0 + 4);
                wv[0] = v0.x; wv[1] = v0.y; wv[2] = v0.z; wv[3] = v0.w;
                wv[4] = v1.x; wv[5] = v1.y; wv[6] = v1.z; wv[7] = v1.w;
            }
            __syncthreads();
            *(uint4*)(Ah + srow * 32 + scol) = a0h;
            *(uint4*)(Ah + (srow + 64) * 32 + scol) = a1h;
            *(uint4*)(Al + srow * 32 + scol) = a0l;
            *(uint4*)(Al + (srow + 64) * 32 + scol) = a1l;
            {
                union { u16 us[8]; uint4 v; } ph, pl;
#pragma unroll
                for (int j = 0; j < 8; j++) split16(wv[j], ph.us[j], pl.us[j]);
                *(uint4*)(Bh + srow * 32 + scol) = ph.v;
                *(uint4*)(Bl + srow * 32 + scol) = pl.v;
            }
            __syncthreads();

            half8 fah[2], fal[2], fbh[4], fbl[4];
#pragma unroll
            for (int i = 0; i < 2; i++) {
                int ra = (w * 32 + i * 16 + lm) * 32 + lk;
                fah[i] = *(const half8*)(Ah + ra);
                fal[i] = *(const half8*)(Al + ra);
            }
#pragma unroll
            for (int i = 0; i < 4; i++) {
                int rb = (i * 16 + lm) * 32 + lk;
                fbh[i] = *(const half8*)(Bh + rb);
                fbl[i] = *(const half8*)(Bl + rb);
            }
#pragma unroll
            for (int mi = 0; mi < 2; mi++)
#pragma unroll
                for (int ni = 0; ni < 4; ni++) {
                    acc[mi][ni] = __builtin_amdgcn_mfma_f32_16x16x32_f16(
                        fal[mi], fbh[ni], acc[mi][ni], 0, 0, 0);
                    acc[mi][ni] = __builtin_amdgcn_mfma_f32_16x16x32_f16(
                        fah[mi], fbl[ni], acc[mi][ni], 0, 0, 0);
                    acc[mi][ni] = __builtin_amdgcn_mfma_f32_16x16x32_f16(
                        fah[mi], fbh[ni], acc[mi][ni], 0, 0, 0);
                }
        }
#pragma unroll
        for (int i = 0; i < 2; i++)
#pragma unroll
            for (int j = 0; j < 4; j++)
#pragma unroll
                for (int r = 0; r < 4; r++) dacc[i][j][r] += (double)acc[i][j][r];
    }

    const int rbase = bm * 128 + w * 32 + (lane >> 4) * 4;
    const int cbase = bn * 64 + lm;
#pragma unroll
    for (int mi = 0; mi < 2; mi++)
#pragma unroll
        for (int ni = 0; ni < 4; ni++) {
            int col = cbase + ni * 16;
            int sel = col >> 10, cc = col & 1023;
            double bias = (sel == 0) ? (double)qbias[cc]
                        : ((sel == 2) ? (double)vbias[cc] : 0.0);
            float* dst = (sel == 0) ? qws : ((sel == 1) ? kws : vws);
#pragma unroll
            for (int r = 0; r < 4; r++) {
                int row = rbase + mi * 16 + r;
                dst[(size_t)row * 1024 + cc] = (float)(dacc[mi][ni][r] + bias);
            }
        }
}

// --- K2a: per-32-group quant of q -> int8 (row-major) + f64 scale ------------
__global__ __launch_bounds__(256) void quant_qk(const float* __restrict__ pre,
                                                signed char* __restrict__ qout,
                                                double* __restrict__ sout) {
    size_t g = (size_t)blockIdx.x * 256 + threadIdx.x;   // 131072 groups
    const float* p = pre + g * 32;
    float v[32];
    float amax = 0.f;
#pragma unroll
    for (int i = 0; i < 8; i++) {
        float4 q4 = ((const float4*)p)[i];
        v[i * 4 + 0] = q4.x; v[i * 4 + 1] = q4.y; v[i * 4 + 2] = q4.z; v[i * 4 + 3] = q4.w;
        amax = fmaxf(amax, fmaxf(fmaxf(fabsf(q4.x), fabsf(q4.y)),
                                 fmaxf(fabsf(q4.z), fabsf(q4.w))));
    }
    double s = fmax((double)amax / 127.0, 1e-8);
    sout[g] = s;
    int pk[8];
#pragma unroll
    for (int i = 0; i < 8; i++) {
        int b0 = (int)fmin(fmax(rint((double)v[i * 4 + 0] / s), -128.0), 127.0);
        int b1 = (int)fmin(fmax(rint((double)v[i * 4 + 1] / s), -128.0), 127.0);
        int b2 = (int)fmin(fmax(rint((double)v[i * 4 + 2] / s), -128.0), 127.0);
        int b3 = (int)fmin(fmax(rint((double)v[i * 4 + 3] / s), -128.0), 127.0);
        pk[i] = (b0 & 255) | ((b1 & 255) << 8) | ((b2 & 255) << 16) | ((b3 & 255) << 24);
    }
    int4* d = (int4*)(qout + g * 32);
    d[0] = make_int4(pk[0], pk[1], pk[2], pk[3]);
    d[1] = make_int4(pk[4], pk[5], pk[6], pk[7]);
}

// --- K2b: per-32-group quant of k -> TRANSPOSED j-major layout ---------------
__global__ __launch_bounds__(256) void quant_k(const float* __restrict__ pre,
                                               int* __restrict__ kT,
                                               double* __restrict__ ksT) {
    size_t g = (size_t)blockIdx.x * 256 + threadIdx.x;   // 131072 groups
    const float* p = pre + g * 32;
    float v[32];
    float amax = 0.f;
#pragma unroll
    for (int i = 0; i < 8; i++) {
        float4 q4 = ((const float4*)p)[i];
        v[i * 4 + 0] = q4.x; v[i * 4 + 1] = q4.y; v[i * 4 + 2] = q4.z; v[i * 4 + 3] = q4.w;
        amax = fmaxf(amax, fmaxf(fmaxf(fabsf(q4.x), fabsf(q4.y)),
                                 fmaxf(fabsf(q4.z), fabsf(q4.w))));
    }
    double s = fmax((double)amax / 127.0, 1e-8);
    int pk[8];
#pragma unroll
    for (int i = 0; i < 8; i++) {
        int b0 = (int)fmin(fmax(rint((double)v[i * 4 + 0] / s), -128.0), 127.0);
        int b1 = (int)fmin(fmax(rint((double)v[i * 4 + 1] / s), -128.0), 127.0);
        int b2 = (int)fmin(fmax(rint((double)v[i * 4 + 2] / s), -128.0), 127.0);
        int b3 = (int)fmin(fmax(rint((double)v[i * 4 + 3] / s), -128.0), 127.0);
        pk[i] = (b0 & 255) | ((b1 & 255) << 8) | ((b2 & 255) << 16) | ((b3 & 255) << 24);
    }
    const int m = (int)((g >> 5) & 1023);
    const int b = (int)(g >> 15);
    const int sub = (int)(g & 31);
    const int h = sub >> 1, pp = sub & 1;
    const int bh = b * 16 + h;
    int* dst = kT + ((size_t)bh * 16 + pp * 8) * 1024 + m;
#pragma unroll
    for (int i = 0; i < 8; i++) dst[i * 1024] = pk[i];
    ksT[((size_t)bh * 2 + pp) * 1024 + m] = s;
}

// --- K3a: partial max|v| over 16-row L-chunks (256 blocks) -------------------
__global__ __launch_bounds__(256) void vmax_part(const float* __restrict__ vws,
                                                 float* __restrict__ pmax) {
    const int lc = blockIdx.x, b = blockIdx.y, t = threadIdx.x;
#pragma unroll
    for (int j = 0; j < 4; j++) {
        int cc = t + j * 256;
        float mx = 0.f;
        for (int l = 0; l < 16; l++)
            mx = fmaxf(mx, fabsf(vws[((size_t)(b * 1024 + lc * 16 + l)) * 1024 + cc]));
        pmax[(size_t)(b * 64 + lc) * 1024 + cc] = mx;
    }
}

// --- K3b: reduce 64 partials -> vs[b*1024+cc] = max(amax/127, eps) f64 -------
__global__ __launch_bounds__(256) void vmax_final(const float* __restrict__ pmax,
                                                  double* __restrict__ vs) {
    int id = blockIdx.x * 256 + threadIdx.x;   // 4096
    int b = id >> 10, cc = id & 1023;
    float mx = 0.f;
    for (int p = 0; p < 64; p++)
        mx = fmaxf(mx, pmax[(size_t)(b * 64 + p) * 1024 + cc]);
    vs[id] = fmax((double)mx / 127.0, 1e-8);
}

// --- K3c: fake-quant v in place (f64 decisions, f32 store) -------------------
__global__ __launch_bounds__(256) void vquant(float* __restrict__ vws,
                                              const double* __restrict__ vs) {
    size_t e = ((size_t)blockIdx.x * 256 + threadIdx.x) * 4;
    int b = (int)(e >> 20), cc = (int)(e & 1023);
    float4 v = *(const float4*)(vws + e);
    double s0 = vs[b * 1024 + cc], s1 = vs[b * 1024 + cc + 1];
    double s2 = vs[b * 1024 + cc + 2], s3 = vs[b * 1024 + cc + 3];
    float4 o;
    o.x = (float)(fmin(fmax(rint((double)v.x / s0), -128.0), 127.0) * s0);
    o.y = (float)(fmin(fmax(rint((double)v.y / s1), -128.0), 127.0) * s1);
    o.z = (float)(fmin(fmax(rint((double)v.z / s2), -128.0), 127.0) * s2);
    o.w = (float)(fmin(fmax(rint((double)v.w / s3), -128.0), 127.0) * s3);
    *(float4*)(vws + e) = o;
}

// ---------------------------------------------------------------------------
// K4: attention (byte-identical to r19's 256.7us version).
// ---------------------------------------------------------------------------
__global__ __launch_bounds__(256) void attn(const signed char* __restrict__ qint,
                                            const int* __restrict__ kT,
                                            const double* __restrict__ qs,
                                            const double* __restrict__ ksT,
                                            const float* __restrict__ vfq,
                                            const float* __restrict__ abias,
                                            u16* __restrict__ ctx) {
    __shared__ int    kTs[16][256];        // 16 KB  (re-used as packed[] below)
    __shared__ double ks0s[256], ks1s[256];//  4 KB
    u32* const packed = (u32*)&kTs[0][0];  // packed[wv*512 + pos]: (n<<16)|m
    const int t = threadIdx.x;
    const int wv = t >> 6, lane = t & 63;
    const int qt = blockIdx.x, h = blockIdx.y, b = blockIdx.z;
    const int row = qt * 4 + wv;
    const size_t qrow = (size_t)(b * 1024 + row);
    const int bh = b * 16 + h;

    const int* qv = (const int*)(qint + qrow * 1024 + h * 64);
    int qd[16];
#pragma unroll
    for (int j = 0; j < 4; j++) {
        int4 tmp = ((const int4*)qv)[j];
        qd[j * 4 + 0] = tmp.x; qd[j * 4 + 1] = tmp.y;
        qd[j * 4 + 2] = tmp.z; qd[j * 4 + 3] = tmp.w;
    }
    const double sq0 = qs[qrow * 32 + 2 * h], sq1 = qs[qrow * 32 + 2 * h + 1];
    const int* kTg = kT + (size_t)bh * 16384;
    const double* ks0g = ksT + (size_t)(bh * 2) * 1024;
    const double* ks1g = ksT + (size_t)(bh * 2 + 1) * 1024;
    const float* ab = abias + (size_t)row * 1024;

    double sd[16];
    for (int c = 0; c < 4; c++) {
        if (c) __syncthreads();
#pragma unroll
        for (int r = 0; r < 4; r++) {
            const int j = wv * 4 + r;
            int4 val = *(const int4*)(kTg + (size_t)j * 1024 + c * 256 + 4 * lane);
            *(int4*)(&kTs[j][4 * lane]) = val;
        }
        ks0s[t] = ks0g[c * 256 + t];
        ks1s[t] = ks1g[c * 256 + t];
        __syncthreads();
#pragma unroll
        for (int s = 0; s < 4; s++) {
            const int ml = s * 64 + lane;
            int I0 = 0, I1 = 0;
#pragma unroll
            for (int j = 0; j < 8; j++)  I0 = dot4(qd[j], kTs[j][ml], I0);
#pragma unroll
            for (int j = 8; j < 16; j++) I1 = dot4(qd[j], kTs[j][ml], I1);
            sd[c * 4 + s] = 0.125 * (sq0 * ks0s[ml] * (double)I0
                                   + sq1 * ks1s[ml] * (double)I1)
                          + (double)ab[c * 256 + ml];
        }
    }

    // softmax (f64): custom exp, single reciprocal
    double mx = sd[0];
#pragma unroll
    for (int it = 1; it < 16; it++) mx = fmax(mx, sd[it]);
#pragma unroll
    for (int off = 1; off < 64; off <<= 1) mx = fmax(mx, __shfl_xor(mx, off));
    double sum = 0.0;
#pragma unroll
    for (int it = 0; it < 16; it++) {
        double e = fexp(sd[it] - mx);
        sd[it] = e;
        sum += e;
    }
#pragma unroll
    for (int off = 1; off < 64; off <<= 1) sum += __shfl_xor(sum, off);
    const double inv = 1.0 / sum;

    // all waves done reading kTs before we overwrite it with packed[]
    __syncthreads();

    // static quant + ballot compaction of nonzeros (ascending m)
    int base = 0;
#pragma unroll
    for (int it = 0; it < 16; it++) {
        double a = sd[it] * inv;
        double nd = fmin(fmax(rint(a * 255.0), 0.0), 255.0);
        int ni = (int)nd;
        unsigned long long mk = __ballot(ni != 0);
        if (ni != 0) {
            int pos = base + (int)__popcll(mk & ((1ull << lane) - 1ull));
            packed[wv * 512 + pos] = ((u32)ni << 16) | (u32)(it * 64 + lane);
        }
        base += (int)__popcll(mk);
    }
    __syncthreads();

    // AV: lane = head dim; iterate compacted list (wave-uniform trip count).
    // r19: no divide (mul by 1/255 const), 4-wide uint4 LDS reads, 4
    // independent accumulators.  Order change proven benign (r12-r14).
    const float r255 = 1.0f / 255.0f;   // compile-time constant
    float acc0 = 0.f, acc1 = 0.f, acc2 = 0.f, acc3 = 0.f;
    const float* vcol = vfq + ((size_t)b * 1024) * 1024 + h * 64 + lane;
    const u32* pk = packed + wv * 512;
    int j = 0;
    for (; j + 4 <= base; j += 4) {
        uint4 p4 = *(const uint4*)(pk + j);
        float v0 = vcol[(size_t)(p4.x & 1023u) * 1024];
        float v1 = vcol[(size_t)(p4.y & 1023u) * 1024];
        float v2 = vcol[(size_t)(p4.z & 1023u) * 1024];
        float v3 = vcol[(size_t)(p4.w & 1023u) * 1024];
        acc0 = fmaf((float)(p4.x >> 16) * r255, v0, acc0);
        acc1 = fmaf((float)(p4.y >> 16) * r255, v1, acc1);
        acc2 = fmaf((float)(p4.z >> 16) * r255, v2, acc2);
        acc3 = fmaf((float)(p4.w >> 16) * r255, v3, acc3);
    }
    for (; j < base; ++j) {
        u32 p = pk[j];
        acc0 = fmaf((float)(p >> 16) * r255, vcol[(size_t)(p & 1023u) * 1024], acc0);
    }
    float acc = (acc0 + acc1) + (acc2 + acc3);
    ctx[qrow * 1024 + h * 64 + lane] = f2b(acc);
}

// --- K5: out = ctx @ w_proj^T + b_proj, bf16 MFMA (post-cliff) ---------------
__global__ __launch_bounds__(256) void gemm_proj(const u16* __restrict__ ctx,
                                                 const u16* __restrict__ wproj,
                                                 const float* __restrict__ bproj,
                                                 float* __restrict__ out) {
    typedef __attribute__((ext_vector_type(8))) short short8;
    __shared__ u16 As[128 * 32], Bs[128 * 32];
    f32x4 acc[4][4];
#pragma unroll
    for (int i = 0; i < 4; i++)
#pragma unroll
        for (int j = 0; j < 4; j++) acc[i][j] = (f32x4){0.f, 0.f, 0.f, 0.f};

    const int t = threadIdx.x;
    const int lane = t & 63, w = t >> 6;
    const int wm = w >> 1, wn = w & 1;
    const int srow = t >> 2, scol = (t & 3) * 8;
    const int lm = lane & 15, lk = (lane >> 4) * 8;
    const int bm = blockIdx.y, bn = blockIdx.x;
    const u16* ap = ctx + (size_t)(bm * 128 + srow) * 1024 + scol;
    const u16* bp = wproj + (size_t)(bn * 128 + srow) * 1024 + scol;

    for (int k0 = 0; k0 < 1024; k0 += 32) {
        uint4 a0 = *(const uint4*)(ap + k0);
        uint4 a1 = *(const uint4*)(ap + (size_t)64 * 1024 + k0);
        uint4 b0 = *(const uint4*)(bp + k0);
        uint4 b1 = *(const uint4*)(bp + (size_t)64 * 1024 + k0);
        __syncthreads();
        *(uint4*)(As + srow * 32 + scol) = a0;
        *(uint4*)(As + (srow + 64) * 32 + scol) = a1;
        *(uint4*)(Bs + srow * 32 + scol) = b0;
        *(uint4*)(Bs + (srow + 64) * 32 + scol) = b1;
        __syncthreads();
        short8 af[4], bfr[4];
#pragma unroll
        for (int i = 0; i < 4; i++) {
            af[i]  = *(const short8*)(As + (wm * 64 + i * 16 + lm) * 32 + lk);
            bfr[i] = *(const short8*)(Bs + (wn * 64 + i * 16 + lm) * 32 + lk);
        }
#pragma unroll
        for (int mi = 0; mi < 4; mi++)
#pragma unroll
            for (int ni = 0; ni < 4; ni++)
                acc[mi][ni] = __builtin_amdgcn_mfma_f32_16x16x32_bf16(
                    af[mi], bfr[ni], acc[mi][ni], 0, 0, 0);
    }

    const int rbase = bm * 128 + wm * 64 + (lane >> 4) * 4;
    const int cbase = bn * 128 + wn * 64 + lm;
#pragma unroll
    for (int mi = 0; mi < 4; mi++)
#pragma unroll
        for (int ni = 0; ni < 4; ni++) {
            int col = cbase + ni * 16;
            float bias = bproj[col];
#pragma unroll
            for (int r = 0; r < 4; r++) {
                int row = rbase + mi * 16 + r;
                out[(size_t)row * 1024 + col] = acc[mi][ni][r] + bias;
            }
        }
}

// ---------------------------------------------------------------------------
extern "C" void kernel_launch(void* const* d_in, const int* in_sizes, int n_in,
                              void* d_out, int out_size, void* d_ws, size_t ws_size,
                              hipStream_t stream) {
    const float* x     = (const float*)d_in[0];
    const float* abias = (const float*)d_in[1];
    const float* wqkv  = (const float*)d_in[2];
    const float* qbias = (const float*)d_in[3];
    const float* vbias = (const float*)d_in[4];
    const float* wproj = (const float*)d_in[5];
    const float* bproj = (const float*)d_in[6];
    float* out = (float*)d_out;

    char* ws = (char*)d_ws;
    float*       qpre    = (float*)(ws + 0);
    float*       kpre    = (float*)(ws + 16777216);
    float*       vfq     = (float*)(ws + 33554432);
    u16*         wprojbf = (u16*)  (ws + 50331648);
    signed char* qint    = (signed char*)(ws + 52428800);
    int*         kT      = (int*)  (ws + 56623104);
    double*      qs      = (double*)(ws + 60817408);
    double*      ksT     = (double*)(ws + 61865984);
    double*      vs      = (double*)(ws + 62914560);
    float*       pmax    = (float*)(ws + 62947328);   // 1MB (262144 f32)
    u16*         ctx     = (u16*)(ws + 0);            // alias qpre
    // transient aliases for presplit x (dead after gemm; region is written
    // only by post-gemm kernels):
    u16*         xh      = (u16*)(ws + 50331648);     // 8MB over wprojbf/qint
    u16*         xl      = (u16*)(ws + 58720256);     // 8MB over kT/qs/ksT..

    presplit<<<4096, 256, 0, stream>>>(x, xh, xl, 4194304);
    gemm_qkv3n<<<dim3(48, 32), 256, 0, stream>>>(xh, xl, wqkv, qbias, vbias,
                                                 qpre, kpre, vfq);
    cvt_bf16w<<<1024, 256, 0, stream>>>(wprojbf, wproj, 1048576);
    quant_qk<<<512, 256, 0, stream>>>(qpre, qint, qs);
    quant_k<<<512, 256, 0, stream>>>(kpre, kT, ksT);
    vmax_part<<<dim3(64, 4), 256, 0, stream>>>(vfq, pmax);
    vmax_final<<<16, 256, 0, stream>>>(pmax, vs);
    vquant<<<4096, 256, 0, stream>>>(vfq, vs);
    attn<<<dim3(256, 16, 4), 256, 0, stream>>>(qint, kT, qs, ksT, vfq, abias, ctx);
    gemm_proj<<<dim3(8, 32), 256, 0, stream>>>(ctx, wprojbf, bproj, out);
}